// Round 12
// baseline (218.882 us; speedup 1.0000x reference)
//
#include <hip/hip_runtime.h>
#include <math.h>

#define NM 50000
#define ND 50000
#define NN 100000   // total nodes
#define DK 256      // feature dim of both sims
#define F  64       // attn feature size
#define SLOPE 0.2f

// proj tiling: 128 rows x 64 cols per block, BK=16, 8x8 micro-tile, 128 threads,
// double-buffered LDS (24 KB), unroll-1 step loop, launch_bounds(128,1) cap 512
#define BRP  128
#define BKP  16
#define NBP  391    // ceil(50000/128)

// edge binning: 256-node buckets
#define NBUCK 391   // ceil(100000/256)
#define BCAP  8192  // per-bucket capacity (avg fill 4092)
#define CH    4096  // edges per bin block

__device__ __forceinline__ void gload_lds16(const void* g, void* l) {
    __builtin_amdgcn_global_load_lds((const __attribute__((address_space(1))) void*)g,
                                     (__attribute__((address_space(3))) void*)l, 16, 0, 0);
}

// ---------------- projection: z = [m_sim @ Wm^T ; d_sim @ Wd^T] ----------------
// R11: 8x4 tile = 89.5us, VGPR 100, VALUBusy 40%; LDS-instr floor for 8x4 is
// 46us (0.375 reads/result). v11: 8x8 tile -> 0.25 reads/result, floor 31us.
// R6's 8x8 failed ONLY from the VGPR-cap snap (128 cap -> GB spill); fix is
// unroll-1 (R11: saved ~70 VGPR) + launch_bounds(128,1) (cap 512, graceful).
// 128 threads: tx=t&7 (8 col groups), ty=t>>3 (16 row groups).
// Swizzle for 16-float rows: stage sw=((l&3)^((l>>2)&3))<<4; read slot k4^(row&3)
// -> 8 rows spaced 64B hit 4 slots = 2-way max (free). Both-sides verified pattern.
__global__ __launch_bounds__(128, 1) void proj_kernel(const float* __restrict__ m_sim,
                                                      const float* __restrict__ d_sim,
                                                      const float* __restrict__ Wm,
                                                      const float* __restrict__ Wd,
                                                      float* __restrict__ z) {
    __shared__ float As[2][BRP * BKP];  // 2 x 8 KB, row stride 64 B
    __shared__ float Ws[2][F * BKP];    // 2 x 4 KB

    int bid  = blockIdx.x;
    bool ism = bid < NBP;
    const float* sim = ism ? m_sim : d_sim;
    const float* W   = ism ? Wm : Wd;
    int row0   = (ism ? bid : bid - NBP) * BRP;
    int nrows  = ism ? NM : ND;
    int zbase  = ism ? 0 : NM;

    int t  = threadIdx.x;     // 0..127
    int tx = t & 7;           // col group 0..7
    int ty = t >> 3;          // row group 0..15
    int w  = t >> 6;          // wave 0..1
    int l  = t & 63;          // lane
    int lrow = l >> 2;        // 0..15 (row within one stage instr's 16-row chunk)
    int sw   = ((l & 3) ^ ((l >> 2) & 3)) << 4;   // swizzled 16B slot in 64B row

    // staging source offsets (bytes). A: 4 instrs/wave (8 chunks), W: 2/wave (4 chunks).
    int aoff[4];
    #pragma unroll
    for (int q = 0; q < 4; ++q) {
        int r  = (w * 4 + q) * 16 + lrow;          // 0..127
        int gr = row0 + r; if (gr > nrows - 1) gr = nrows - 1;
        aoff[q] = gr * (DK * 4) + sw;
    }
    int woff[2];
    #pragma unroll
    for (int q = 0; q < 2; ++q) {
        int r = (w * 2 + q) * 16 + lrow;           // 0..63
        woff[q] = r * (DK * 4) + sw;
    }

    // read-side swizzle keys
    int akey = ty & 3;
    int wkey = tx & 3;

    float acc[8][8];
    #pragma unroll
    for (int i = 0; i < 8; ++i)
        #pragma unroll
        for (int j = 0; j < 8; ++j) acc[i][j] = 0.f;

    const int NK = DK / BKP;   // 16

    // prologue: stage step 0 into buf 0
    #pragma unroll
    for (int q = 0; q < 4; ++q)
        gload_lds16((const char*)sim + (size_t)aoff[q], (char*)As[0] + (w * 4 + q) * 1024);
    #pragma unroll
    for (int q = 0; q < 2; ++q)
        gload_lds16((const char*)W + (size_t)woff[q], (char*)Ws[0] + (w * 2 + q) * 1024);

    #pragma unroll 1
    for (int step = 0; step < NK; ++step) {
        int cur = step & 1;
        __syncthreads();   // drains vmcnt: stage(cur) done; buf^1 readers done

        if (step + 1 < NK) {   // issue next stage async; flies under compute below
            int koff = (step + 1) * (BKP * 4);   // 64 B per K-step
            #pragma unroll
            for (int q = 0; q < 4; ++q)
                gload_lds16((const char*)sim + (size_t)(aoff[q] + koff),
                            (char*)As[cur ^ 1] + (w * 4 + q) * 1024);
            #pragma unroll
            for (int q = 0; q < 2; ++q)
                gload_lds16((const char*)W + (size_t)(woff[q] + koff),
                            (char*)Ws[cur ^ 1] + (w * 2 + q) * 1024);
        }

        #pragma unroll
        for (int k4 = 0; k4 < BKP / 4; ++k4) {
            float4 a[8];
            #pragma unroll
            for (int i = 0; i < 8; ++i)
                a[i] = *(const float4*)((const char*)As[cur] + (i * 16 + ty) * 64
                                        + ((k4 ^ akey) << 4));
            #pragma unroll
            for (int j = 0; j < 8; ++j) {
                float4 wv = *(const float4*)((const char*)Ws[cur] + (j * 8 + tx) * 64
                                             + ((k4 ^ wkey) << 4));
                #pragma unroll
                for (int i = 0; i < 8; ++i)
                    acc[i][j] += a[i].x * wv.x + a[i].y * wv.y
                               + a[i].z * wv.z + a[i].w * wv.w;
            }
        }
    }

    #pragma unroll
    for (int i = 0; i < 8; ++i) {
        int r = row0 + i * 16 + ty;
        if (r < nrows) {
            float* zr = z + (size_t)(zbase + r) * F;
            #pragma unroll
            for (int j = 0; j < 8; ++j) zr[j * 8 + tx] = acc[i][j];
        }
    }
}

// ---------------- stage 1: bin edges into 256-node buckets (LDS-grouped) ----------------
__global__ __launch_bounds__(512) void bin_kernel(const int* __restrict__ src,
                                                  const int* __restrict__ dst,
                                                  int* __restrict__ srcb_g,
                                                  int* __restrict__ dstb_g,
                                                  int* __restrict__ bcur,   // [512] zeroed
                                                  int E) {
    __shared__ int cnt[512], sc[512], lcur[512], gbase[512];
    __shared__ int srcb_l[CH], dstb_l[CH];

    int t    = threadIdx.x;
    int base = blockIdx.x * CH;
    int chunkN = E - base; if (chunkN > CH) chunkN = CH;

    cnt[t] = 0;
    __syncthreads();

    int ss[8], ds[8];
    #pragma unroll
    for (int e = 0; e < 8; ++e) {
        int k = base + e * 512 + t;
        if (e * 512 + t < chunkN) {
            ds[e] = dst[k];
            ss[e] = src[k];
            atomicAdd(&cnt[ds[e] >> 8], 1);
        }
    }
    __syncthreads();

    sc[t] = cnt[t];
    __syncthreads();
    for (int off = 1; off < 512; off <<= 1) {
        int v = (t >= off) ? sc[t - off] : 0;
        __syncthreads();
        sc[t] += v;
        __syncthreads();
    }
    int lexcl_t = sc[t] - cnt[t];
    sc[t] = lexcl_t;
    lcur[t] = lexcl_t;
    gbase[t] = atomicAdd(&bcur[t], cnt[t]);
    __syncthreads();

    #pragma unroll
    for (int e = 0; e < 8; ++e) {
        if (e * 512 + t < chunkN) {
            int b = ds[e] >> 8;
            int p = atomicAdd(&lcur[b], 1);
            srcb_l[p] = ss[e];
            dstb_l[p] = ds[e];
        }
    }
    __syncthreads();

    for (int idx = t; idx < chunkN; idx += 512) {
        int d = dstb_l[idx];
        int b = d >> 8;
        int g = b * BCAP + gbase[b] + (idx - sc[b]);
        srcb_g[g] = srcb_l[idx];
        dstb_g[g] = d;
    }
}

// ---------------- stage 2a: per-node degree from binned dst (LDS atomics) ----------------
__global__ __launch_bounds__(256) void deg_kernel(const int* __restrict__ dstb_g,
                                                  const int* __restrict__ bcur,
                                                  int* __restrict__ deg) {
    __shared__ int dcnt[256];
    int b = blockIdx.x;
    int t = threadIdx.x;
    int node0 = b << 8;
    int nn = NN - node0; if (nn > 256) nn = 256;
    dcnt[t] = 0;
    __syncthreads();
    int nbe = bcur[b];
    const int* dp = dstb_g + (size_t)b * BCAP;
    for (int i = t; i < nbe; i += 256)
        atomicAdd(&dcnt[dp[i] & 255], 1);
    __syncthreads();
    if (t < nn) deg[node0 + t] = dcnt[t];
}

// ---------------- block-level inclusive scan (1024 elems / block) ----------------
__global__ __launch_bounds__(256) void scanA(const int* __restrict__ deg,
                                             int* __restrict__ incl,   // = offs+1
                                             int* __restrict__ bsums) {
    __shared__ int sd[256];
    int tid  = threadIdx.x;
    int base = blockIdx.x * 1024 + tid * 4;
    int v[4];
    int run = 0;
    #pragma unroll
    for (int j = 0; j < 4; ++j) {
        int i = base + j;
        int x = (i < NN) ? deg[i] : 0;
        run += x;
        v[j] = run;
    }
    sd[tid] = run;
    __syncthreads();
    for (int off = 1; off < 256; off <<= 1) {
        int t = (tid >= off) ? sd[tid - off] : 0;
        __syncthreads();
        sd[tid] += t;
        __syncthreads();
    }
    int texcl = sd[tid] - run;
    #pragma unroll
    for (int j = 0; j < 4; ++j) {
        int i = base + j;
        if (i < NN) incl[i] = texcl + v[j];
    }
    if (tid == 255) bsums[blockIdx.x] = sd[255];
}

// ---------------- scan of the block sums (exclusive, in place) ----------------
__global__ void scanB(int* __restrict__ bsums, int nb) {
    __shared__ int sd[128];
    int tid = threadIdx.x;
    int x = (tid < nb) ? bsums[tid] : 0;
    sd[tid] = x;
    __syncthreads();
    for (int off = 1; off < 128; off <<= 1) {
        int t = (tid >= off) ? sd[tid - off] : 0;
        __syncthreads();
        sd[tid] += t;
        __syncthreads();
    }
    if (tid < nb) bsums[tid] = sd[tid] - x;
}

// ---------------- finalize offsets ----------------
__global__ __launch_bounds__(256) void scanC(int* __restrict__ offs,
                                             const int* __restrict__ bsums) {
    int base = blockIdx.x * 1024 + threadIdx.x * 4;
    int add  = bsums[blockIdx.x];
    #pragma unroll
    for (int j = 0; j < 4; ++j) {
        int i = base + j;
        if (i < NN) offs[i + 1] += add;
    }
    if (blockIdx.x == 0 && threadIdx.x == 0) offs[0] = 0;
}

// ---------------- stage 2b: XCD-local scatter into CSR ----------------
__global__ __launch_bounds__(256) void scatter2(const int* __restrict__ srcb_g,
                                                const int* __restrict__ dstb_g,
                                                const int* __restrict__ bcur,
                                                const int* __restrict__ offs,
                                                int* __restrict__ csr) {
    __shared__ int lcur[256];
    int b = blockIdx.x;
    int t = threadIdx.x;
    int node0 = b << 8;
    int nn = NN - node0; if (nn > 256) nn = 256;
    if (t < nn) lcur[t] = offs[node0 + t];
    __syncthreads();
    int nbe = bcur[b];
    const int* sp = srcb_g + (size_t)b * BCAP;
    const int* dp = dstb_g + (size_t)b * BCAP;
    for (int i = t; i < nbe; i += 256) {
        int d = dp[i];
        int s = sp[i];
        int pos = atomicAdd(&lcur[d & 255], 1);
        csr[pos] = s;
    }
}

// ---------------- fused per-dst-node: scores + online softmax + aggregation + elu ----------------
__global__ __launch_bounds__(256) void gat_kernel(const float* __restrict__ z,
                                                  const int* __restrict__ offs,
                                                  const int* __restrict__ csr_src,
                                                  float* __restrict__ out) {
    int tid  = threadIdx.x;
    int node = blockIdx.x * 4 + (tid >> 6);
    int lane = tid & 63;
    int g    = lane >> 4;     // edge slot 0..3
    int i    = lane & 15;     // feature quad 0..15
    int beg = offs[node];
    int end = offs[node + 1];

    float4 zd = *(const float4*)&z[(size_t)node * F + i * 4];

    float  m = -1e30f, ssum = 0.f;
    float4 h = {0.f, 0.f, 0.f, 0.f};

    for (int j = beg; j < end; j += 8) {
        int j0 = j + g, j1 = j + 4 + g;
        bool v0 = j0 < end, v1 = j1 < end;
        int s0 = csr_src[v0 ? j0 : beg];
        int s1 = csr_src[v1 ? j1 : beg];
        float4 a = *(const float4*)&z[(size_t)s0 * F + i * 4];
        float4 b = *(const float4*)&z[(size_t)s1 * F + i * 4];
        float p0 = a.x * zd.x + a.y * zd.y + a.z * zd.z + a.w * zd.w;
        float p1 = b.x * zd.x + b.y * zd.y + b.z * zd.z + b.w * zd.w;
        #pragma unroll
        for (int o = 1; o < 16; o <<= 1) {
            p0 += __shfl_xor(p0, o, 64);
            p1 += __shfl_xor(p1, o, 64);
        }
        float e0 = (p0 > 0.f) ? p0 : SLOPE * p0;
        float e1 = (p1 > 0.f) ? p1 : SLOPE * p1;
        e0 = v0 ? e0 : -1e30f;
        e1 = v1 ? e1 : -1e30f;
        float nm = fmaxf(m, fmaxf(e0, e1));
        float sc = __expf(m - nm);
        float ex0 = v0 ? __expf(e0 - nm) : 0.f;
        float ex1 = v1 ? __expf(e1 - nm) : 0.f;
        ssum = ssum * sc + ex0 + ex1;
        h.x = h.x * sc + ex0 * a.x + ex1 * b.x;
        h.y = h.y * sc + ex0 * a.y + ex1 * b.y;
        h.z = h.z * sc + ex0 * a.z + ex1 * b.z;
        h.w = h.w * sc + ex0 * a.w + ex1 * b.w;
        m = nm;
    }

    float M = fmaxf(m, __shfl_xor(m, 16, 64));
    M = fmaxf(M, __shfl_xor(M, 32, 64));
    float sc = __expf(m - M);
    float ss = ssum * sc;
    ss += __shfl_xor(ss, 16, 64);
    ss += __shfl_xor(ss, 32, 64);
    h.x *= sc; h.y *= sc; h.z *= sc; h.w *= sc;
    h.x += __shfl_xor(h.x, 16, 64); h.x += __shfl_xor(h.x, 32, 64);
    h.y += __shfl_xor(h.y, 16, 64); h.y += __shfl_xor(h.y, 32, 64);
    h.z += __shfl_xor(h.z, 16, 64); h.z += __shfl_xor(h.z, 32, 64);
    h.w += __shfl_xor(h.w, 16, 64); h.w += __shfl_xor(h.w, 32, 64);

    if (g == 0) {
        float rs = 1.0f / ss;
        bool has = end > beg;
        float4 o;
        o.x = has ? h.x * rs : 0.f;
        o.y = has ? h.y * rs : 0.f;
        o.z = has ? h.z * rs : 0.f;
        o.w = has ? h.w * rs : 0.f;
        o.x = (o.x > 0.f) ? o.x : (__expf(o.x) - 1.f);
        o.y = (o.y > 0.f) ? o.y : (__expf(o.y) - 1.f);
        o.z = (o.z > 0.f) ? o.z : (__expf(o.z) - 1.f);
        o.w = (o.w > 0.f) ? o.w : (__expf(o.w) - 1.f);
        *(float4*)&out[(size_t)node * F + i * 4] = o;
    }
}

extern "C" void kernel_launch(void* const* d_in, const int* in_sizes, int n_in,
                              void* d_out, int out_size, void* d_ws, size_t ws_size,
                              hipStream_t stream) {
    const float* m_sim = (const float*)d_in[0];
    const float* d_sim = (const float*)d_in[1];
    const float* Wm    = (const float*)d_in[2];
    const float* Wd    = (const float*)d_in[3];
    const int*   src   = (const int*)d_in[4];
    const int*   dst   = (const int*)d_in[5];
    int E = in_sizes[4];
    float* out = (float*)d_out;

    char* ws = (char*)d_ws;
    float* z      = (float*)ws; ws += (size_t)NN * F * 4;
    int*   deg    = (int*)ws;   ws += (size_t)NN * 4;
    int*   offs   = (int*)ws;   ws += (size_t)(NN + 1) * 4;
    int*   bsums  = (int*)ws;   ws += 128 * 4;
    int*   bcur   = (int*)ws;   ws += 512 * 4;
    int*   csr    = (int*)ws;   ws += (size_t)E * 4;
    int*   srcb_g = (int*)ws;   ws += (size_t)NBUCK * BCAP * 4;
    int*   dstb_g = (int*)ws;   ws += (size_t)NBUCK * BCAP * 4;

    hipMemsetAsync(bcur, 0, 512 * 4, stream);

    int nchunks = (E + CH - 1) / CH;
    bin_kernel<<<nchunks, 512, 0, stream>>>(src, dst, srcb_g, dstb_g, bcur, E);
    proj_kernel<<<NBP * 2, 128, 0, stream>>>(m_sim, d_sim, Wm, Wd, z);
    deg_kernel<<<NBUCK, 256, 0, stream>>>(dstb_g, bcur, deg);
    int nb = (NN + 1023) / 1024;   // 98
    scanA<<<nb, 256, 0, stream>>>(deg, offs + 1, bsums);
    scanB<<<1, 128, 0, stream>>>(bsums, nb);
    scanC<<<nb, 256, 0, stream>>>(offs, bsums);
    scatter2<<<NBUCK, 256, 0, stream>>>(srcb_g, dstb_g, bcur, offs, csr);
    gat_kernel<<<NN / 4, 256, 0, stream>>>(z, offs, csr, out);
}

// Round 13
// 158.388 us; speedup vs baseline: 1.3819x; 1.3819x over previous
//
#include <hip/hip_runtime.h>
#include <math.h>

#define NM 50000
#define ND 50000
#define NN 100000   // total nodes
#define DK 256      // feature dim of both sims
#define F  64       // attn feature size
#define SLOPE 0.2f

// proj: MFMA bf16-split GEMM. 64 rows x 64 cols per block, 256 thr (4 waves),
// wave = 16-row stripe x four 16x16 tiles, K chunks of 32, dbuf LDS.
#define NBZ  782    // ceil(50000/64) blocks per half

// edge binning: 256-node buckets
#define NBUCK 391   // ceil(100000/256)
#define BCAP  8192  // per-bucket capacity (avg fill 4092)
#define CH    4096  // edges per bin block

typedef short bf16x8 __attribute__((ext_vector_type(8)));
typedef float f32x4  __attribute__((ext_vector_type(4)));

__device__ __forceinline__ void gload_lds16(const void* g, void* l) {
    __builtin_amdgcn_global_load_lds((const __attribute__((address_space(1))) void*)g,
                                     (__attribute__((address_space(3))) void*)l, 16, 0, 0);
}

// fp32 -> (hi, lo) bf16 split, round-to-nearest-even both halves.
__device__ __forceinline__ void cvt8(const float4& a0, const float4& a1,
                                     bf16x8& hi, bf16x8& lo) {
    float v[8] = {a0.x, a0.y, a0.z, a0.w, a1.x, a1.y, a1.z, a1.w};
    #pragma unroll
    for (int e = 0; e < 8; ++e) {
        unsigned u  = __float_as_uint(v[e]);
        unsigned r  = u + 0x7FFF + ((u >> 16) & 1);
        unsigned short hb = (unsigned short)(r >> 16);
        float hf = __uint_as_float(((unsigned)hb) << 16);
        float lf = v[e] - hf;
        unsigned ul = __float_as_uint(lf);
        unsigned rl = ul + 0x7FFF + ((ul >> 16) & 1);
        hi[e] = (short)hb;
        lo[e] = (short)(rl >> 16);
    }
}

// ---------------- projection: z = [m_sim @ Wm^T ; d_sim @ Wd^T] ----------------
// bf16-split MFMA: x=hi+lo; x*y ~ hi*hi + hi*lo + lo*hi (error ~2^-16; z err
// ~1e-3 vs 0.13 threshold). mfma_f32_16x16x32_bf16 layouts: D col=lane&15,
// row=(lane>>4)*4+reg (HW-verified m89); A row=lane&15 / B col=lane&15,
// k=(lane>>4)*8+e (documented convention — absmax will catch a swap).
// LDS: A,W chunk tiles 64x32 fp32, dbuf (32 KB), staged via gload_lds with the
// verified pre-swizzled-source pattern (slot ^= row&7 at 16B granule) and the
// same XOR on reads -> <=2-way conflicts. Scalar path (R11, 89.5us) was
// LDS-pipe-bound at 0.375 reads/result; MFMA needs 10 reads per wave-chunk
// (floor ~10us) + cvt VALU ~12us + HBM 16us.
__global__ __launch_bounds__(256, 2) void proj_kernel(const float* __restrict__ m_sim,
                                                      const float* __restrict__ d_sim,
                                                      const float* __restrict__ Wm,
                                                      const float* __restrict__ Wd,
                                                      float* __restrict__ z) {
    __shared__ float As[2][64 * 32];   // 2 x 8 KB, row stride 128 B
    __shared__ float Ws_[2][64 * 32];  // 2 x 8 KB

    int bid  = blockIdx.x;
    bool ism = bid < NBZ;
    const float* sim = ism ? m_sim : d_sim;
    const float* W   = ism ? Wm : Wd;
    int row0   = (ism ? bid : bid - NBZ) * 64;
    int nrows  = ism ? NM : ND;
    int zbase  = ism ? 0 : NM;

    int t = threadIdx.x;      // 0..255
    int l = t & 63;           // lane
    int w = t >> 6;           // wave 0..3

    // staging: per wave per chunk: 2 A instrs + 2 W instrs (1 KB each = 8 rows)
    int srow = l >> 3;        // 0..7
    int ssw  = ((l & 7) ^ (srow & 7)) << 4;   // pre-swizzled 16B slot in 128B row

    size_t aoff[2], woff[2];
    #pragma unroll
    for (int q = 0; q < 2; ++q) {
        int r  = w * 16 + q * 8 + srow;        // 0..63
        int gr = row0 + r; if (gr > nrows - 1) gr = nrows - 1;
        aoff[q] = (size_t)gr * (DK * 4) + ssw;
        woff[q] = (size_t)r  * (DK * 4) + ssw;
    }

    // frag-read addressing
    int frow = l & 15;        // A row within wave stripe / B col within tile
    int kg   = l >> 4;        // k-group 0..3, k = kg*8 + e
    int s0   = kg * 2;        // first 16B slot of the 32B k-pair
    int arow = w * 16 + frow; // row in 64-row A tile
    int aof0 = arow * 128 + (((s0    ) ^ (arow & 7)) << 4);
    int aof1 = arow * 128 + (((s0 + 1) ^ (arow & 7)) << 4);

    f32x4 acc[4];
    #pragma unroll
    for (int j = 0; j < 4; ++j) acc[j] = (f32x4){0.f, 0.f, 0.f, 0.f};

    const int NK = 8;   // 256 / 32

    // prologue: stage chunk 0 into buf 0
    #pragma unroll
    for (int q = 0; q < 2; ++q) {
        gload_lds16((const char*)sim + aoff[q], (char*)As[0]  + (w * 16 + q * 8) * 128);
        gload_lds16((const char*)W   + woff[q], (char*)Ws_[0] + (w * 16 + q * 8) * 128);
    }

    #pragma unroll 1
    for (int step = 0; step < NK; ++step) {
        int cur = step & 1;
        __syncthreads();   // drains vmcnt: stage(cur) done; buf^1 readers done

        if (step + 1 < NK) {   // issue next stage async; flies under compute below
            int koff = (step + 1) * 128;   // 128 B per K-chunk per row
            #pragma unroll
            for (int q = 0; q < 2; ++q) {
                gload_lds16((const char*)sim + aoff[q] + koff,
                            (char*)As[cur ^ 1]  + (w * 16 + q * 8) * 128);
                gload_lds16((const char*)W   + woff[q] + koff,
                            (char*)Ws_[cur ^ 1] + (w * 16 + q * 8) * 128);
            }
        }

        // A fragment: this wave's 16 rows, k = kg*8 + 0..7
        float4 a0 = *(const float4*)((const char*)As[cur] + aof0);
        float4 a1 = *(const float4*)((const char*)As[cur] + aof1);
        bf16x8 ahi, alo;
        cvt8(a0, a1, ahi, alo);

        #pragma unroll
        for (int j = 0; j < 4; ++j) {
            int wrow = j * 16 + frow;   // W row = output col
            float4 b0 = *(const float4*)((const char*)Ws_[cur] + wrow * 128
                                         + (((s0    ) ^ (wrow & 7)) << 4));
            float4 b1 = *(const float4*)((const char*)Ws_[cur] + wrow * 128
                                         + (((s0 + 1) ^ (wrow & 7)) << 4));
            bf16x8 bhi, blo;
            cvt8(b0, b1, bhi, blo);
            acc[j] = __builtin_amdgcn_mfma_f32_16x16x32_bf16(ahi, bhi, acc[j], 0, 0, 0);
            acc[j] = __builtin_amdgcn_mfma_f32_16x16x32_bf16(ahi, blo, acc[j], 0, 0, 0);
            acc[j] = __builtin_amdgcn_mfma_f32_16x16x32_bf16(alo, bhi, acc[j], 0, 0, 0);
        }
    }

    // D layout (verified m89): col = lane&15, row = (lane>>4)*4 + reg
    #pragma unroll
    for (int j = 0; j < 4; ++j) {
        #pragma unroll
        for (int reg = 0; reg < 4; ++reg) {
            int r = row0 + w * 16 + kg * 4 + reg;
            if (r < nrows)
                z[(size_t)(zbase + r) * F + j * 16 + frow] = acc[j][reg];
        }
    }
}

// ---------------- stage 1: bin edges into 256-node buckets (LDS-grouped) ----------------
__global__ __launch_bounds__(512) void bin_kernel(const int* __restrict__ src,
                                                  const int* __restrict__ dst,
                                                  int* __restrict__ srcb_g,
                                                  int* __restrict__ dstb_g,
                                                  int* __restrict__ bcur,   // [512] zeroed
                                                  int E) {
    __shared__ int cnt[512], sc[512], lcur[512], gbase[512];
    __shared__ int srcb_l[CH], dstb_l[CH];

    int t    = threadIdx.x;
    int base = blockIdx.x * CH;
    int chunkN = E - base; if (chunkN > CH) chunkN = CH;

    cnt[t] = 0;
    __syncthreads();

    int ss[8], ds[8];
    #pragma unroll
    for (int e = 0; e < 8; ++e) {
        int k = base + e * 512 + t;
        if (e * 512 + t < chunkN) {
            ds[e] = dst[k];
            ss[e] = src[k];
            atomicAdd(&cnt[ds[e] >> 8], 1);
        }
    }
    __syncthreads();

    sc[t] = cnt[t];
    __syncthreads();
    for (int off = 1; off < 512; off <<= 1) {
        int v = (t >= off) ? sc[t - off] : 0;
        __syncthreads();
        sc[t] += v;
        __syncthreads();
    }
    int lexcl_t = sc[t] - cnt[t];
    sc[t] = lexcl_t;
    lcur[t] = lexcl_t;
    gbase[t] = atomicAdd(&bcur[t], cnt[t]);
    __syncthreads();

    #pragma unroll
    for (int e = 0; e < 8; ++e) {
        if (e * 512 + t < chunkN) {
            int b = ds[e] >> 8;
            int p = atomicAdd(&lcur[b], 1);
            srcb_l[p] = ss[e];
            dstb_l[p] = ds[e];
        }
    }
    __syncthreads();

    for (int idx = t; idx < chunkN; idx += 512) {
        int d = dstb_l[idx];
        int b = d >> 8;
        int g = b * BCAP + gbase[b] + (idx - sc[b]);
        srcb_g[g] = srcb_l[idx];
        dstb_g[g] = d;
    }
}

// ---------------- stage 2a: per-node degree from binned dst (LDS atomics) ----------------
__global__ __launch_bounds__(256) void deg_kernel(const int* __restrict__ dstb_g,
                                                  const int* __restrict__ bcur,
                                                  int* __restrict__ deg) {
    __shared__ int dcnt[256];
    int b = blockIdx.x;
    int t = threadIdx.x;
    int node0 = b << 8;
    int nn = NN - node0; if (nn > 256) nn = 256;
    dcnt[t] = 0;
    __syncthreads();
    int nbe = bcur[b];
    const int* dp = dstb_g + (size_t)b * BCAP;
    for (int i = t; i < nbe; i += 256)
        atomicAdd(&dcnt[dp[i] & 255], 1);
    __syncthreads();
    if (t < nn) deg[node0 + t] = dcnt[t];
}

// ---------------- block-level inclusive scan (1024 elems / block) ----------------
__global__ __launch_bounds__(256) void scanA(const int* __restrict__ deg,
                                             int* __restrict__ incl,   // = offs+1
                                             int* __restrict__ bsums) {
    __shared__ int sd[256];
    int tid  = threadIdx.x;
    int base = blockIdx.x * 1024 + tid * 4;
    int v[4];
    int run = 0;
    #pragma unroll
    for (int j = 0; j < 4; ++j) {
        int i = base + j;
        int x = (i < NN) ? deg[i] : 0;
        run += x;
        v[j] = run;
    }
    sd[tid] = run;
    __syncthreads();
    for (int off = 1; off < 256; off <<= 1) {
        int t = (tid >= off) ? sd[tid - off] : 0;
        __syncthreads();
        sd[tid] += t;
        __syncthreads();
    }
    int texcl = sd[tid] - run;
    #pragma unroll
    for (int j = 0; j < 4; ++j) {
        int i = base + j;
        if (i < NN) incl[i] = texcl + v[j];
    }
    if (tid == 255) bsums[blockIdx.x] = sd[255];
}

// ---------------- scan of the block sums (exclusive, in place) ----------------
__global__ void scanB(int* __restrict__ bsums, int nb) {
    __shared__ int sd[128];
    int tid = threadIdx.x;
    int x = (tid < nb) ? bsums[tid] : 0;
    sd[tid] = x;
    __syncthreads();
    for (int off = 1; off < 128; off <<= 1) {
        int t = (tid >= off) ? sd[tid - off] : 0;
        __syncthreads();
        sd[tid] += t;
        __syncthreads();
    }
    if (tid < nb) bsums[tid] = sd[tid] - x;
}

// ---------------- finalize offsets ----------------
__global__ __launch_bounds__(256) void scanC(int* __restrict__ offs,
                                             const int* __restrict__ bsums) {
    int base = blockIdx.x * 1024 + threadIdx.x * 4;
    int add  = bsums[blockIdx.x];
    #pragma unroll
    for (int j = 0; j < 4; ++j) {
        int i = base + j;
        if (i < NN) offs[i + 1] += add;
    }
    if (blockIdx.x == 0 && threadIdx.x == 0) offs[0] = 0;
}

// ---------------- stage 2b: XCD-local scatter into CSR ----------------
__global__ __launch_bounds__(256) void scatter2(const int* __restrict__ srcb_g,
                                                const int* __restrict__ dstb_g,
                                                const int* __restrict__ bcur,
                                                const int* __restrict__ offs,
                                                int* __restrict__ csr) {
    __shared__ int lcur[256];
    int b = blockIdx.x;
    int t = threadIdx.x;
    int node0 = b << 8;
    int nn = NN - node0; if (nn > 256) nn = 256;
    if (t < nn) lcur[t] = offs[node0 + t];
    __syncthreads();
    int nbe = bcur[b];
    const int* sp = srcb_g + (size_t)b * BCAP;
    const int* dp = dstb_g + (size_t)b * BCAP;
    for (int i = t; i < nbe; i += 256) {
        int d = dp[i];
        int s = sp[i];
        int pos = atomicAdd(&lcur[d & 255], 1);
        csr[pos] = s;
    }
}

// ---------------- fused per-dst-node: scores + online softmax + aggregation + elu ----------------
__global__ __launch_bounds__(256) void gat_kernel(const float* __restrict__ z,
                                                  const int* __restrict__ offs,
                                                  const int* __restrict__ csr_src,
                                                  float* __restrict__ out) {
    int tid  = threadIdx.x;
    int node = blockIdx.x * 4 + (tid >> 6);
    int lane = tid & 63;
    int g    = lane >> 4;     // edge slot 0..3
    int i    = lane & 15;     // feature quad 0..15
    int beg = offs[node];
    int end = offs[node + 1];

    float4 zd = *(const float4*)&z[(size_t)node * F + i * 4];

    float  m = -1e30f, ssum = 0.f;
    float4 h = {0.f, 0.f, 0.f, 0.f};

    for (int j = beg; j < end; j += 8) {
        int j0 = j + g, j1 = j + 4 + g;
        bool v0 = j0 < end, v1 = j1 < end;
        int s0 = csr_src[v0 ? j0 : beg];
        int s1 = csr_src[v1 ? j1 : beg];
        float4 a = *(const float4*)&z[(size_t)s0 * F + i * 4];
        float4 b = *(const float4*)&z[(size_t)s1 * F + i * 4];
        float p0 = a.x * zd.x + a.y * zd.y + a.z * zd.z + a.w * zd.w;
        float p1 = b.x * zd.x + b.y * zd.y + b.z * zd.z + b.w * zd.w;
        #pragma unroll
        for (int o = 1; o < 16; o <<= 1) {
            p0 += __shfl_xor(p0, o, 64);
            p1 += __shfl_xor(p1, o, 64);
        }
        float e0 = (p0 > 0.f) ? p0 : SLOPE * p0;
        float e1 = (p1 > 0.f) ? p1 : SLOPE * p1;
        e0 = v0 ? e0 : -1e30f;
        e1 = v1 ? e1 : -1e30f;
        float nm = fmaxf(m, fmaxf(e0, e1));
        float sc = __expf(m - nm);
        float ex0 = v0 ? __expf(e0 - nm) : 0.f;
        float ex1 = v1 ? __expf(e1 - nm) : 0.f;
        ssum = ssum * sc + ex0 + ex1;
        h.x = h.x * sc + ex0 * a.x + ex1 * b.x;
        h.y = h.y * sc + ex0 * a.y + ex1 * b.y;
        h.z = h.z * sc + ex0 * a.z + ex1 * b.z;
        h.w = h.w * sc + ex0 * a.w + ex1 * b.w;
        m = nm;
    }

    float M = fmaxf(m, __shfl_xor(m, 16, 64));
    M = fmaxf(M, __shfl_xor(M, 32, 64));
    float sc = __expf(m - M);
    float ss = ssum * sc;
    ss += __shfl_xor(ss, 16, 64);
    ss += __shfl_xor(ss, 32, 64);
    h.x *= sc; h.y *= sc; h.z *= sc; h.w *= sc;
    h.x += __shfl_xor(h.x, 16, 64); h.x += __shfl_xor(h.x, 32, 64);
    h.y += __shfl_xor(h.y, 16, 64); h.y += __shfl_xor(h.y, 32, 64);
    h.z += __shfl_xor(h.z, 16, 64); h.z += __shfl_xor(h.z, 32, 64);
    h.w += __shfl_xor(h.w, 16, 64); h.w += __shfl_xor(h.w, 32, 64);

    if (g == 0) {
        float rs = 1.0f / ss;
        bool has = end > beg;
        float4 o;
        o.x = has ? h.x * rs : 0.f;
        o.y = has ? h.y * rs : 0.f;
        o.z = has ? h.z * rs : 0.f;
        o.w = has ? h.w * rs : 0.f;
        o.x = (o.x > 0.f) ? o.x : (__expf(o.x) - 1.f);
        o.y = (o.y > 0.f) ? o.y : (__expf(o.y) - 1.f);
        o.z = (o.z > 0.f) ? o.z : (__expf(o.z) - 1.f);
        o.w = (o.w > 0.f) ? o.w : (__expf(o.w) - 1.f);
        *(float4*)&out[(size_t)node * F + i * 4] = o;
    }
}

extern "C" void kernel_launch(void* const* d_in, const int* in_sizes, int n_in,
                              void* d_out, int out_size, void* d_ws, size_t ws_size,
                              hipStream_t stream) {
    const float* m_sim = (const float*)d_in[0];
    const float* d_sim = (const float*)d_in[1];
    const float* Wm    = (const float*)d_in[2];
    const float* Wd    = (const float*)d_in[3];
    const int*   src   = (const int*)d_in[4];
    const int*   dst   = (const int*)d_in[5];
    int E = in_sizes[4];
    float* out = (float*)d_out;

    char* ws = (char*)d_ws;
    float* z      = (float*)ws; ws += (size_t)NN * F * 4;
    int*   deg    = (int*)ws;   ws += (size_t)NN * 4;
    int*   offs   = (int*)ws;   ws += (size_t)(NN + 1) * 4;
    int*   bsums  = (int*)ws;   ws += 128 * 4;
    int*   bcur   = (int*)ws;   ws += 512 * 4;
    int*   csr    = (int*)ws;   ws += (size_t)E * 4;
    int*   srcb_g = (int*)ws;   ws += (size_t)NBUCK * BCAP * 4;
    int*   dstb_g = (int*)ws;   ws += (size_t)NBUCK * BCAP * 4;

    hipMemsetAsync(bcur, 0, 512 * 4, stream);

    int nchunks = (E + CH - 1) / CH;
    bin_kernel<<<nchunks, 512, 0, stream>>>(src, dst, srcb_g, dstb_g, bcur, E);
    proj_kernel<<<NBZ * 2, 256, 0, stream>>>(m_sim, d_sim, Wm, Wd, z);
    deg_kernel<<<NBUCK, 256, 0, stream>>>(dstb_g, bcur, deg);
    int nb = (NN + 1023) / 1024;   // 98
    scanA<<<nb, 256, 0, stream>>>(deg, offs + 1, bsums);
    scanB<<<1, 128, 0, stream>>>(bsums, nb);
    scanC<<<nb, 256, 0, stream>>>(offs, bsums);
    scatter2<<<NBUCK, 256, 0, stream>>>(srcb_g, dstb_g, bcur, offs, csr);
    gat_kernel<<<NN / 4, 256, 0, stream>>>(z, offs, csr, out);
}

// Round 14
// 157.416 us; speedup vs baseline: 1.3905x; 1.0062x over previous
//
#include <hip/hip_runtime.h>
#include <math.h>

#define NM 50000
#define ND 50000
#define NN 100000   // total nodes
#define DK 256      // feature dim of both sims
#define F  64       // attn feature size
#define SLOPE 0.2f

// proj: MFMA bf16-split GEMM. 64 rows x 64 cols per block, 256 thr (4 waves).
#define NBZ  782    // ceil(50000/64) blocks per half

// edge binning: 256-node buckets
#define NBUCK 391   // ceil(100000/256)
#define BCAP  8192  // per-bucket capacity (avg fill 4092)
#define CH    4096  // edges per bin block

typedef short bf16x8 __attribute__((ext_vector_type(8)));
typedef float f32x4  __attribute__((ext_vector_type(4)));

__device__ __forceinline__ void gload_lds16(const void* g, void* l) {
    __builtin_amdgcn_global_load_lds((const __attribute__((address_space(1))) void*)g,
                                     (__attribute__((address_space(3))) void*)l, 16, 0, 0);
}

// fp32 -> (hi, lo) bf16 split, round-to-nearest-even both halves.
__device__ __forceinline__ void cvt8(const float4& a0, const float4& a1,
                                     bf16x8& hi, bf16x8& lo) {
    float v[8] = {a0.x, a0.y, a0.z, a0.w, a1.x, a1.y, a1.z, a1.w};
    #pragma unroll
    for (int e = 0; e < 8; ++e) {
        unsigned u  = __float_as_uint(v[e]);
        unsigned r  = u + 0x7FFF + ((u >> 16) & 1);
        unsigned short hb = (unsigned short)(r >> 16);
        float hf = __uint_as_float(((unsigned)hb) << 16);
        float lf = v[e] - hf;
        unsigned ul = __float_as_uint(lf);
        unsigned rl = ul + 0x7FFF + ((ul >> 16) & 1);
        hi[e] = (short)hb;
        lo[e] = (short)(rl >> 16);
    }
}

// ---------------- projection: z = [m_sim @ Wm^T ; d_sim @ Wd^T] ----------------
// R13 forensics: cvt8 ~56 VALU; each wave re-converted the shared W tile every
// chunk (10 cvt8/chunk/wave = 4480 VALU/wave vs 96 MFMA). v13: convert W ONCE
// per block into LDS bf16 hi/lo (reg-staged writes -> free write-side XOR
// swizzle), K-loop reads B as bf16x8 directly. In-loop cvt 10->2 cvt8 (A only),
// staging 4->2 gload/chunk/wave. LDS 16+64=80KB -> 2 blocks/CU (8 waves/CU).
// B-read banks: ps=ls^(row&7): 16 lanes spread 8 slot-groups x4 banks, 2-way free.
__global__ __launch_bounds__(256, 1) void proj_kernel(const float* __restrict__ m_sim,
                                                      const float* __restrict__ d_sim,
                                                      const float* __restrict__ Wm,
                                                      const float* __restrict__ Wd,
                                                      float* __restrict__ z) {
    __shared__ float As[2][64 * 32];   // 2 x 8 KB fp32 A chunk, row stride 128 B
    __shared__ short Whi[64 * 256];    // 32 KB, physical slot layout ps = ls^(row&7)
    __shared__ short Wlo[64 * 256];    // 32 KB

    int bid  = blockIdx.x;
    bool ism = bid < NBZ;
    const float* sim = ism ? m_sim : d_sim;
    const float* W   = ism ? Wm : Wd;
    int row0   = (ism ? bid : bid - NBZ) * 64;
    int nrows  = ism ? NM : ND;
    int zbase  = ism ? 0 : NM;

    int t = threadIdx.x;      // 0..255
    int l = t & 63;           // lane
    int w = t >> 6;           // wave 0..3

    // ---- A staging (per wave per chunk: 2 instrs, 8 rows each) ----
    int srow = l >> 3;        // 0..7
    int ssw  = ((l & 7) ^ (srow & 7)) << 4;   // pre-swizzled 16B slot in 128B row
    size_t aoff[2];
    #pragma unroll
    for (int q = 0; q < 2; ++q) {
        int r  = w * 16 + q * 8 + srow;        // 0..63
        int gr = row0 + r; if (gr > nrows - 1) gr = nrows - 1;
        aoff[q] = (size_t)gr * (DK * 4) + ssw;
    }

    // issue A chunk-0 stage FIRST (HBM latency flies under the W conversion)
    #pragma unroll
    for (int q = 0; q < 2; ++q)
        gload_lds16((const char*)sim + aoff[q], (char*)As[0] + (w * 16 + q * 8) * 128);

    // ---- W -> LDS bf16 hi/lo, once per block (reg-staged, write-side XOR) ----
    {
        int r = t >> 2;                 // row 0..63
        int q = t & 3;                  // k-quarter
        const float4* wr = (const float4*)(W + (size_t)r * DK);
        #pragma unroll
        for (int i = 0; i < 8; ++i) {
            int ls = q * 8 + i;         // logical slot 0..31 (k = ls*8..ls*8+7)
            float4 b0 = wr[ls * 2], b1 = wr[ls * 2 + 1];
            bf16x8 hi, lo;
            cvt8(b0, b1, hi, lo);
            int ps = ls ^ (r & 7);      // physical slot
            *(bf16x8*)&Whi[r * 256 + ps * 8] = hi;
            *(bf16x8*)&Wlo[r * 256 + ps * 8] = lo;
        }
    }

    // ---- frag-read addressing ----
    int frow = l & 15;        // A row within wave stripe / B col within tile
    int kg   = l >> 4;        // k-group 0..3, k = kg*8 + e
    int s0   = kg * 2;        // first 16B slot of the 32B k-pair (A chunk rows)
    int arow = w * 16 + frow; // row in 64-row A tile
    int aof0 = arow * 128 + (((s0    ) ^ (arow & 7)) << 4);
    int aof1 = arow * 128 + (((s0 + 1) ^ (arow & 7)) << 4);

    f32x4 acc[4];
    #pragma unroll
    for (int j = 0; j < 4; ++j) acc[j] = (f32x4){0.f, 0.f, 0.f, 0.f};

    const int NK = 8;   // 256 / 32

    #pragma unroll 1
    for (int step = 0; step < NK; ++step) {
        int cur = step & 1;
        __syncthreads();   // drains vmcnt (stage(cur)) + W-cvt LDS writes on step 0

        if (step + 1 < NK) {   // issue next A stage async; flies under compute
            int koff = (step + 1) * 128;
            #pragma unroll
            for (int q = 0; q < 2; ++q)
                gload_lds16((const char*)sim + aoff[q] + koff,
                            (char*)As[cur ^ 1] + (w * 16 + q * 8) * 128);
        }

        // A fragment: this wave's 16 rows, k = kg*8 + 0..7
        float4 a0 = *(const float4*)((const char*)As[cur] + aof0);
        float4 a1 = *(const float4*)((const char*)As[cur] + aof1);
        bf16x8 ahi, alo;
        cvt8(a0, a1, ahi, alo);

        int ls = step * 4 + kg;          // logical W slot for this chunk/k-group
        #pragma unroll
        for (int j = 0; j < 4; ++j) {
            int wrow = j * 16 + frow;    // W row = output col
            int ps = ls ^ (wrow & 7);
            bf16x8 bhi = *(const bf16x8*)&Whi[wrow * 256 + ps * 8];
            bf16x8 blo = *(const bf16x8*)&Wlo[wrow * 256 + ps * 8];
            acc[j] = __builtin_amdgcn_mfma_f32_16x16x32_bf16(ahi, bhi, acc[j], 0, 0, 0);
            acc[j] = __builtin_amdgcn_mfma_f32_16x16x32_bf16(ahi, blo, acc[j], 0, 0, 0);
            acc[j] = __builtin_amdgcn_mfma_f32_16x16x32_bf16(alo, bhi, acc[j], 0, 0, 0);
        }
    }

    // D layout (verified m89): col = lane&15, row = (lane>>4)*4 + reg
    #pragma unroll
    for (int j = 0; j < 4; ++j) {
        #pragma unroll
        for (int reg = 0; reg < 4; ++reg) {
            int r = row0 + w * 16 + kg * 4 + reg;
            if (r < nrows)
                z[(size_t)(zbase + r) * F + j * 16 + frow] = acc[j][reg];
        }
    }
}

// ---------------- stage 1: bin edges into 256-node buckets (LDS-grouped) ----------------
// Packed stream: pk = (src<<8) | (dst&255)  (src<2^17, fits 25 bits) -> halves
// global write vs (src,dst) pairs. Bucket index kept in LDS-only side array.
__global__ __launch_bounds__(512) void bin_kernel(const int* __restrict__ src,
                                                  const int* __restrict__ dst,
                                                  int* __restrict__ pkb_g,
                                                  int* __restrict__ bcur,   // [512] zeroed
                                                  int E) {
    __shared__ int cnt[512], sc[512], lcur[512], gbase[512];
    __shared__ int pkb_l[CH];
    __shared__ int bkt_l[CH];

    int t    = threadIdx.x;
    int base = blockIdx.x * CH;
    int chunkN = E - base; if (chunkN > CH) chunkN = CH;

    cnt[t] = 0;
    __syncthreads();

    int ss[8], ds[8];
    #pragma unroll
    for (int e = 0; e < 8; ++e) {
        int k = base + e * 512 + t;
        if (e * 512 + t < chunkN) {
            ds[e] = dst[k];
            ss[e] = src[k];
            atomicAdd(&cnt[ds[e] >> 8], 1);
        }
    }
    __syncthreads();

    sc[t] = cnt[t];
    __syncthreads();
    for (int off = 1; off < 512; off <<= 1) {
        int v = (t >= off) ? sc[t - off] : 0;
        __syncthreads();
        sc[t] += v;
        __syncthreads();
    }
    int lexcl_t = sc[t] - cnt[t];
    sc[t] = lexcl_t;
    lcur[t] = lexcl_t;
    gbase[t] = atomicAdd(&bcur[t], cnt[t]);
    __syncthreads();

    #pragma unroll
    for (int e = 0; e < 8; ++e) {
        if (e * 512 + t < chunkN) {
            int b = ds[e] >> 8;
            int p = atomicAdd(&lcur[b], 1);
            pkb_l[p] = (ss[e] << 8) | (ds[e] & 255);
            bkt_l[p] = b;
        }
    }
    __syncthreads();

    for (int idx = t; idx < chunkN; idx += 512) {
        int b = bkt_l[idx];
        int g = b * BCAP + gbase[b] + (idx - sc[b]);
        pkb_g[g] = pkb_l[idx];
    }
}

// ---------------- stage 2a: per-node degree from binned stream (LDS atomics) ----------------
__global__ __launch_bounds__(256) void deg_kernel(const int* __restrict__ pkb_g,
                                                  const int* __restrict__ bcur,
                                                  int* __restrict__ deg) {
    __shared__ int dcnt[256];
    int b = blockIdx.x;
    int t = threadIdx.x;
    int node0 = b << 8;
    int nn = NN - node0; if (nn > 256) nn = 256;
    dcnt[t] = 0;
    __syncthreads();
    int nbe = bcur[b];
    const int* pp = pkb_g + (size_t)b * BCAP;
    for (int i = t; i < nbe; i += 256)
        atomicAdd(&dcnt[pp[i] & 255], 1);
    __syncthreads();
    if (t < nn) deg[node0 + t] = dcnt[t];
}

// ---------------- block-level inclusive scan (1024 elems / block) ----------------
__global__ __launch_bounds__(256) void scanA(const int* __restrict__ deg,
                                             int* __restrict__ incl,   // = offs+1
                                             int* __restrict__ bsums) {
    __shared__ int sd[256];
    int tid  = threadIdx.x;
    int base = blockIdx.x * 1024 + tid * 4;
    int v[4];
    int run = 0;
    #pragma unroll
    for (int j = 0; j < 4; ++j) {
        int i = base + j;
        int x = (i < NN) ? deg[i] : 0;
        run += x;
        v[j] = run;
    }
    sd[tid] = run;
    __syncthreads();
    for (int off = 1; off < 256; off <<= 1) {
        int t = (tid >= off) ? sd[tid - off] : 0;
        __syncthreads();
        sd[tid] += t;
        __syncthreads();
    }
    int texcl = sd[tid] - run;
    #pragma unroll
    for (int j = 0; j < 4; ++j) {
        int i = base + j;
        if (i < NN) incl[i] = texcl + v[j];
    }
    if (tid == 255) bsums[blockIdx.x] = sd[255];
}

// ---------------- scan of the block sums (exclusive, in place) ----------------
__global__ void scanB(int* __restrict__ bsums, int nb) {
    __shared__ int sd[128];
    int tid = threadIdx.x;
    int x = (tid < nb) ? bsums[tid] : 0;
    sd[tid] = x;
    __syncthreads();
    for (int off = 1; off < 128; off <<= 1) {
        int t = (tid >= off) ? sd[tid - off] : 0;
        __syncthreads();
        sd[tid] += t;
        __syncthreads();
    }
    if (tid < nb) bsums[tid] = sd[tid] - x;
}

// ---------------- finalize offsets ----------------
__global__ __launch_bounds__(256) void scanC(int* __restrict__ offs,
                                             const int* __restrict__ bsums) {
    int base = blockIdx.x * 1024 + threadIdx.x * 4;
    int add  = bsums[blockIdx.x];
    #pragma unroll
    for (int j = 0; j < 4; ++j) {
        int i = base + j;
        if (i < NN) offs[i + 1] += add;
    }
    if (blockIdx.x == 0 && threadIdx.x == 0) offs[0] = 0;
}

// ---------------- stage 2b: XCD-local scatter into CSR ----------------
__global__ __launch_bounds__(256) void scatter2(const int* __restrict__ pkb_g,
                                                const int* __restrict__ bcur,
                                                const int* __restrict__ offs,
                                                int* __restrict__ csr) {
    __shared__ int lcur[256];
    int b = blockIdx.x;
    int t = threadIdx.x;
    int node0 = b << 8;
    int nn = NN - node0; if (nn > 256) nn = 256;
    if (t < nn) lcur[t] = offs[node0 + t];
    __syncthreads();
    int nbe = bcur[b];
    const int* pp = pkb_g + (size_t)b * BCAP;
    for (int i = t; i < nbe; i += 256) {
        int pk = pp[i];
        int pos = atomicAdd(&lcur[pk & 255], 1);
        csr[pos] = pk >> 8;
    }
}

// ---------------- fused per-dst-node: scores + online softmax + aggregation + elu ----------------
__global__ __launch_bounds__(256) void gat_kernel(const float* __restrict__ z,
                                                  const int* __restrict__ offs,
                                                  const int* __restrict__ csr_src,
                                                  float* __restrict__ out) {
    int tid  = threadIdx.x;
    int node = blockIdx.x * 4 + (tid >> 6);
    int lane = tid & 63;
    int g    = lane >> 4;     // edge slot 0..3
    int i    = lane & 15;     // feature quad 0..15
    int beg = offs[node];
    int end = offs[node + 1];

    float4 zd = *(const float4*)&z[(size_t)node * F + i * 4];

    float  m = -1e30f, ssum = 0.f;
    float4 h = {0.f, 0.f, 0.f, 0.f};

    for (int j = beg; j < end; j += 8) {
        int j0 = j + g, j1 = j + 4 + g;
        bool v0 = j0 < end, v1 = j1 < end;
        int s0 = csr_src[v0 ? j0 : beg];
        int s1 = csr_src[v1 ? j1 : beg];
        float4 a = *(const float4*)&z[(size_t)s0 * F + i * 4];
        float4 b = *(const float4*)&z[(size_t)s1 * F + i * 4];
        float p0 = a.x * zd.x + a.y * zd.y + a.z * zd.z + a.w * zd.w;
        float p1 = b.x * zd.x + b.y * zd.y + b.z * zd.z + b.w * zd.w;
        #pragma unroll
        for (int o = 1; o < 16; o <<= 1) {
            p0 += __shfl_xor(p0, o, 64);
            p1 += __shfl_xor(p1, o, 64);
        }
        float e0 = (p0 > 0.f) ? p0 : SLOPE * p0;
        float e1 = (p1 > 0.f) ? p1 : SLOPE * p1;
        e0 = v0 ? e0 : -1e30f;
        e1 = v1 ? e1 : -1e30f;
        float nm = fmaxf(m, fmaxf(e0, e1));
        float sc = __expf(m - nm);
        float ex0 = v0 ? __expf(e0 - nm) : 0.f;
        float ex1 = v1 ? __expf(e1 - nm) : 0.f;
        ssum = ssum * sc + ex0 + ex1;
        h.x = h.x * sc + ex0 * a.x + ex1 * b.x;
        h.y = h.y * sc + ex0 * a.y + ex1 * b.y;
        h.z = h.z * sc + ex0 * a.z + ex1 * b.z;
        h.w = h.w * sc + ex0 * a.w + ex1 * b.w;
        m = nm;
    }

    float M = fmaxf(m, __shfl_xor(m, 16, 64));
    M = fmaxf(M, __shfl_xor(M, 32, 64));
    float sc = __expf(m - M);
    float ss = ssum * sc;
    ss += __shfl_xor(ss, 16, 64);
    ss += __shfl_xor(ss, 32, 64);
    h.x *= sc; h.y *= sc; h.z *= sc; h.w *= sc;
    h.x += __shfl_xor(h.x, 16, 64); h.x += __shfl_xor(h.x, 32, 64);
    h.y += __shfl_xor(h.y, 16, 64); h.y += __shfl_xor(h.y, 32, 64);
    h.z += __shfl_xor(h.z, 16, 64); h.z += __shfl_xor(h.z, 32, 64);
    h.w += __shfl_xor(h.w, 16, 64); h.w += __shfl_xor(h.w, 32, 64);

    if (g == 0) {
        float rs = 1.0f / ss;
        bool has = end > beg;
        float4 o;
        o.x = has ? h.x * rs : 0.f;
        o.y = has ? h.y * rs : 0.f;
        o.z = has ? h.z * rs : 0.f;
        o.w = has ? h.w * rs : 0.f;
        o.x = (o.x > 0.f) ? o.x : (__expf(o.x) - 1.f);
        o.y = (o.y > 0.f) ? o.y : (__expf(o.y) - 1.f);
        o.z = (o.z > 0.f) ? o.z : (__expf(o.z) - 1.f);
        o.w = (o.w > 0.f) ? o.w : (__expf(o.w) - 1.f);
        *(float4*)&out[(size_t)node * F + i * 4] = o;
    }
}

extern "C" void kernel_launch(void* const* d_in, const int* in_sizes, int n_in,
                              void* d_out, int out_size, void* d_ws, size_t ws_size,
                              hipStream_t stream) {
    const float* m_sim = (const float*)d_in[0];
    const float* d_sim = (const float*)d_in[1];
    const float* Wm    = (const float*)d_in[2];
    const float* Wd    = (const float*)d_in[3];
    const int*   src   = (const int*)d_in[4];
    const int*   dst   = (const int*)d_in[5];
    int E = in_sizes[4];
    float* out = (float*)d_out;

    char* ws = (char*)d_ws;
    float* z      = (float*)ws; ws += (size_t)NN * F * 4;
    int*   deg    = (int*)ws;   ws += (size_t)NN * 4;
    int*   offs   = (int*)ws;   ws += (size_t)(NN + 1) * 4;
    int*   bsums  = (int*)ws;   ws += 128 * 4;
    int*   bcur   = (int*)ws;   ws += 512 * 4;
    int*   csr    = (int*)ws;   ws += (size_t)E * 4;
    int*   pkb_g  = (int*)ws;   ws += (size_t)NBUCK * BCAP * 4;

    hipMemsetAsync(bcur, 0, 512 * 4, stream);

    int nchunks = (E + CH - 1) / CH;
    bin_kernel<<<nchunks, 512, 0, stream>>>(src, dst, pkb_g, bcur, E);
    proj_kernel<<<NBZ * 2, 256, 0, stream>>>(m_sim, d_sim, Wm, Wd, z);
    deg_kernel<<<NBUCK, 256, 0, stream>>>(pkb_g, bcur, deg);
    int nb = (NN + 1023) / 1024;   // 98
    scanA<<<nb, 256, 0, stream>>>(deg, offs + 1, bsums);
    scanB<<<1, 128, 0, stream>>>(bsums, nb);
    scanC<<<nb, 256, 0, stream>>>(offs, bsums);
    scatter2<<<NBUCK, 256, 0, stream>>>(pkb_g, bcur, offs, csr);
    gat_kernel<<<NN / 4, 256, 0, stream>>>(z, offs, csr, out);
}

// Round 16
// 147.992 us; speedup vs baseline: 1.4790x; 1.0637x over previous
//
#include <hip/hip_runtime.h>
#include <math.h>

#define NM 50000
#define ND 50000
#define NN 100000   // total nodes
#define DK 256      // feature dim of both sims
#define F  64       // attn feature size
#define SLOPE 0.2f

#define NBZ   782   // ceil(50000/64) proj blocks per half
#define NPROJ (NBZ * 2)

// edge binning: 256-node buckets
#define NBUCK 391   // ceil(100000/256)
#define BCAP  8192  // per-bucket capacity (avg fill 4092)
#define CH    4096  // edges per bin block

typedef short bf16x8 __attribute__((ext_vector_type(8)));
typedef float f32x4  __attribute__((ext_vector_type(4)));

__device__ __forceinline__ void gload_lds16(const void* g, void* l) {
    __builtin_amdgcn_global_load_lds((const __attribute__((address_space(1))) void*)g,
                                     (__attribute__((address_space(3))) void*)l, 16, 0, 0);
}

// fp32 -> (hi, lo) bf16 split, rne both halves
__device__ __forceinline__ void cvt8(const float4& a0, const float4& a1,
                                     bf16x8& hi, bf16x8& lo) {
    float v[8] = {a0.x, a0.y, a0.z, a0.w, a1.x, a1.y, a1.z, a1.w};
    #pragma unroll
    for (int e = 0; e < 8; ++e) {
        unsigned u  = __float_as_uint(v[e]);
        unsigned r  = u + 0x7FFF + ((u >> 16) & 1);
        unsigned short hb = (unsigned short)(r >> 16);
        float hf = __uint_as_float(((unsigned)hb) << 16);
        float lf = v[e] - hf;
        unsigned ul = __float_as_uint(lf);
        unsigned rl = ul + 0x7FFF + ((ul >> 16) & 1);
        hi[e] = (short)hb;
        lo[e] = (short)(rl >> 16);
    }
}

// ================= fused kernel 1: bin (blocks 0..nchunks-1)  ∥  proj (rest) =================
// R15 post-mortem: dropping x*lo(W) gave absmax 0.1328 > 0.13 — 2-term is past
// the precision cliff. v16 restores the 3-term split (R13/R14: absmax 0.0156)
// inside R15's fused structure. proj LDS = A dbuf 16KB + Whi 32KB + Wlo 32KB =
// 80KB (R13/R14-proven) -> 2 blocks/CU. Fusion still hides bin under proj.
__global__ __launch_bounds__(256, 1) void fused1(const float* __restrict__ m_sim,
                                                 const float* __restrict__ d_sim,
                                                 const float* __restrict__ Wm,
                                                 const float* __restrict__ Wd,
                                                 float* __restrict__ z,
                                                 const int* __restrict__ src,
                                                 const int* __restrict__ dst,
                                                 int* __restrict__ pkb_g,
                                                 int* __restrict__ bcur,
                                                 int nchunks, int E) {
    __shared__ __align__(16) char smem[81920];   // 80 KB, union of both paths
    int t = threadIdx.x;

    if ((int)blockIdx.x < nchunks) {
        // ---------------- bin path (uses 42 KB) ----------------
        int* cnt   = (int*)smem;          // 512
        int* scx   = cnt + 512;           // 512 exclusive offsets
        int* sp    = scx + 512;           // 256 pair sums
        int* lcur  = sp + 256;            // 512
        int* gbase = lcur + 512;          // 512
        int* pkb_l = gbase + 512;         // 4096
        int* bkt_l = pkb_l + CH;          // 4096

        int base = blockIdx.x * CH;
        int chunkN = E - base; if (chunkN > CH) chunkN = CH;

        cnt[t] = 0; cnt[t + 256] = 0;
        __syncthreads();

        int ss[16], ds[16];
        #pragma unroll
        for (int e = 0; e < 16; ++e) {
            int k = base + e * 256 + t;
            if (e * 256 + t < chunkN) {
                ds[e] = dst[k];
                ss[e] = src[k];
                atomicAdd(&cnt[ds[e] >> 8], 1);
            }
        }
        __syncthreads();

        // scan 512 counters with 256 threads (pair-sum scan)
        int a0 = cnt[2 * t], a1 = cnt[2 * t + 1];
        sp[t] = a0 + a1;
        __syncthreads();
        for (int off = 1; off < 256; off <<= 1) {
            int v = (t >= off) ? sp[t - off] : 0;
            __syncthreads();
            sp[t] += v;
            __syncthreads();
        }
        int pe = sp[t] - (a0 + a1);       // exclusive pair prefix
        scx[2 * t]     = pe;
        scx[2 * t + 1] = pe + a0;
        lcur[2 * t]     = pe;
        lcur[2 * t + 1] = pe + a0;
        gbase[2 * t]     = atomicAdd(&bcur[2 * t],     a0);
        gbase[2 * t + 1] = atomicAdd(&bcur[2 * t + 1], a1);
        __syncthreads();

        #pragma unroll
        for (int e = 0; e < 16; ++e) {
            if (e * 256 + t < chunkN) {
                int b = ds[e] >> 8;
                int p = atomicAdd(&lcur[b], 1);
                pkb_l[p] = (ss[e] << 8) | (ds[e] & 255);
                bkt_l[p] = b;
            }
        }
        __syncthreads();

        for (int idx = t; idx < chunkN; idx += 256) {
            int b = bkt_l[idx];
            int g = b * BCAP + gbase[b] + (idx - scx[b]);
            pkb_g[g] = pkb_l[idx];
        }
        return;
    }

    // ---------------- proj path (80 KB) ----------------
    float* As  = (float*)smem;            // 2 x 64x32 fp32 = 16 KB
    short* Whi = (short*)(smem + 16384);  // 64 x 256 bf16 = 32 KB, ps = ls^(row&7)
    short* Wlo = (short*)(smem + 49152);  // 32 KB

    int bid  = blockIdx.x - nchunks;
    bool ism = bid < NBZ;
    const float* sim = ism ? m_sim : d_sim;
    const float* W   = ism ? Wm : Wd;
    int row0   = (ism ? bid : bid - NBZ) * 64;
    int nrows  = ism ? NM : ND;
    int zbase  = ism ? 0 : NM;

    int l = t & 63;
    int w = t >> 6;

    // A staging (per wave per chunk: 2 instrs, 8 rows each)
    int srow = l >> 3;
    int ssw  = ((l & 7) ^ (srow & 7)) << 4;
    size_t aoff[2];
    #pragma unroll
    for (int q = 0; q < 2; ++q) {
        int r  = w * 16 + q * 8 + srow;
        int gr = row0 + r; if (gr > nrows - 1) gr = nrows - 1;
        aoff[q] = (size_t)gr * (DK * 4) + ssw;
    }
    // issue A chunk-0 stage first (flies under W conversion)
    #pragma unroll
    for (int q = 0; q < 2; ++q)
        gload_lds16((const char*)sim + aoff[q], (char*)As + (w * 16 + q * 8) * 128);

    // W -> LDS bf16 hi+lo, once per block (reg-staged, write-side XOR)
    {
        int r = t >> 2;                   // row 0..63
        int q = t & 3;                    // k-quarter
        const float4* wr = (const float4*)(W + (size_t)r * DK);
        #pragma unroll
        for (int i = 0; i < 8; ++i) {
            int ls = q * 8 + i;
            float4 b0 = wr[ls * 2], b1 = wr[ls * 2 + 1];
            bf16x8 hi, lo;
            cvt8(b0, b1, hi, lo);
            int ps = ls ^ (r & 7);
            *(bf16x8*)&Whi[r * 256 + ps * 8] = hi;
            *(bf16x8*)&Wlo[r * 256 + ps * 8] = lo;
        }
    }

    int frow = l & 15;
    int kg   = l >> 4;
    int s0   = kg * 2;
    int arow = w * 16 + frow;
    int aof0 = arow * 128 + (((s0    ) ^ (arow & 7)) << 4);
    int aof1 = arow * 128 + (((s0 + 1) ^ (arow & 7)) << 4);

    f32x4 acc[4];
    #pragma unroll
    for (int j = 0; j < 4; ++j) acc[j] = (f32x4){0.f, 0.f, 0.f, 0.f};

    const int NK = 8;

    #pragma unroll 1
    for (int step = 0; step < NK; ++step) {
        int cur = step & 1;
        __syncthreads();   // drains vmcnt(stage cur) + W-cvt writes on step 0

        if (step + 1 < NK) {
            int koff = (step + 1) * 128;
            #pragma unroll
            for (int q = 0; q < 2; ++q)
                gload_lds16((const char*)sim + aoff[q] + koff,
                            (char*)As + (cur ^ 1) * 2048 * 4 + (w * 16 + q * 8) * 128);
        }

        float4 a0 = *(const float4*)((const char*)As + cur * 2048 * 4 + aof0);
        float4 a1 = *(const float4*)((const char*)As + cur * 2048 * 4 + aof1);
        bf16x8 ahi, alo;
        cvt8(a0, a1, ahi, alo);

        int ls = step * 4 + kg;
        #pragma unroll
        for (int j = 0; j < 4; ++j) {
            int wrow = j * 16 + frow;
            int ps = ls ^ (wrow & 7);
            bf16x8 bhi = *(const bf16x8*)&Whi[wrow * 256 + ps * 8];
            bf16x8 blo = *(const bf16x8*)&Wlo[wrow * 256 + ps * 8];
            acc[j] = __builtin_amdgcn_mfma_f32_16x16x32_bf16(ahi, bhi, acc[j], 0, 0, 0);
            acc[j] = __builtin_amdgcn_mfma_f32_16x16x32_bf16(ahi, blo, acc[j], 0, 0, 0);
            acc[j] = __builtin_amdgcn_mfma_f32_16x16x32_bf16(alo, bhi, acc[j], 0, 0, 0);
        }
    }

    // D layout (verified m89): col = lane&15, row = (lane>>4)*4 + reg
    #pragma unroll
    for (int j = 0; j < 4; ++j) {
        #pragma unroll
        for (int reg = 0; reg < 4; ++reg) {
            int r = row0 + w * 16 + kg * 4 + reg;
            if (r < nrows)
                z[(size_t)(zbase + r) * F + j * 16 + frow] = acc[j][reg];
        }
    }
}

// ---------------- exclusive scan of bucket totals ----------------
__global__ __launch_bounds__(512) void scanBuck(const int* __restrict__ bcur,
                                                int* __restrict__ bbase) {
    __shared__ int sd[512];
    int t = threadIdx.x;
    int x = (t < NBUCK) ? bcur[t] : 0;
    sd[t] = x;
    __syncthreads();
    for (int off = 1; off < 512; off <<= 1) {
        int v = (t >= off) ? sd[t - off] : 0;
        __syncthreads();
        sd[t] += v;
        __syncthreads();
    }
    if (t < NBUCK) bbase[t] = sd[t] - x;
}

// ---------------- per-bucket: degree hist + local scan + offs + scatter ----------------
__global__ __launch_bounds__(256) void scatter3(const int* __restrict__ pkb_g,
                                                const int* __restrict__ bcur,
                                                const int* __restrict__ bbase,
                                                int* __restrict__ offs,
                                                int* __restrict__ csr) {
    __shared__ int dcnt[256], loc[256], lcur[256];
    int b = blockIdx.x;
    int t = threadIdx.x;
    int node0 = b << 8;
    int nbe  = bcur[b];
    int base = bbase[b];
    const int* pp = pkb_g + (size_t)b * BCAP;

    dcnt[t] = 0;
    __syncthreads();
    for (int i = t; i < nbe; i += 256)
        atomicAdd(&dcnt[pp[i] & 255], 1);
    __syncthreads();

    int x = dcnt[t];
    loc[t] = x;
    __syncthreads();
    for (int off = 1; off < 256; off <<= 1) {
        int v = (t >= off) ? loc[t - off] : 0;
        __syncthreads();
        loc[t] += v;
        __syncthreads();
    }
    int excl = loc[t] - x;
    int node = node0 + t;
    if (node < NN) offs[node] = base + excl;
    if (b == NBUCK - 1 && t == 0) offs[NN] = base + nbe;
    lcur[t] = base + excl;
    __syncthreads();

    for (int i = t; i < nbe; i += 256) {
        int pk = pp[i];
        int pos = atomicAdd(&lcur[pk & 255], 1);
        csr[pos] = pk >> 8;
    }
}

// ---------------- fused per-dst-node: scores + online softmax + aggregation + elu ----------------
__global__ __launch_bounds__(256) void gat_kernel(const float* __restrict__ z,
                                                  const int* __restrict__ offs,
                                                  const int* __restrict__ csr_src,
                                                  float* __restrict__ out) {
    int tid  = threadIdx.x;
    int node = blockIdx.x * 4 + (tid >> 6);
    int lane = tid & 63;
    int g    = lane >> 4;     // edge slot 0..3
    int i    = lane & 15;     // feature quad 0..15
    int beg = offs[node];
    int end = offs[node + 1];

    float4 zd = *(const float4*)&z[(size_t)node * F + i * 4];

    float  m = -1e30f, ssum = 0.f;
    float4 h = {0.f, 0.f, 0.f, 0.f};

    for (int j = beg; j < end; j += 8) {
        int j0 = j + g, j1 = j + 4 + g;
        bool v0 = j0 < end, v1 = j1 < end;
        int s0 = csr_src[v0 ? j0 : beg];
        int s1 = csr_src[v1 ? j1 : beg];
        float4 a = *(const float4*)&z[(size_t)s0 * F + i * 4];
        float4 b = *(const float4*)&z[(size_t)s1 * F + i * 4];
        float p0 = a.x * zd.x + a.y * zd.y + a.z * zd.z + a.w * zd.w;
        float p1 = b.x * zd.x + b.y * zd.y + b.z * zd.z + b.w * zd.w;
        #pragma unroll
        for (int o = 1; o < 16; o <<= 1) {
            p0 += __shfl_xor(p0, o, 64);
            p1 += __shfl_xor(p1, o, 64);
        }
        float e0 = (p0 > 0.f) ? p0 : SLOPE * p0;
        float e1 = (p1 > 0.f) ? p1 : SLOPE * p1;
        e0 = v0 ? e0 : -1e30f;
        e1 = v1 ? e1 : -1e30f;
        float nm = fmaxf(m, fmaxf(e0, e1));
        float sc = __expf(m - nm);
        float ex0 = v0 ? __expf(e0 - nm) : 0.f;
        float ex1 = v1 ? __expf(e1 - nm) : 0.f;
        ssum = ssum * sc + ex0 + ex1;
        h.x = h.x * sc + ex0 * a.x + ex1 * b.x;
        h.y = h.y * sc + ex0 * a.y + ex1 * b.y;
        h.z = h.z * sc + ex0 * a.z + ex1 * b.z;
        h.w = h.w * sc + ex0 * a.w + ex1 * b.w;
        m = nm;
    }

    float M = fmaxf(m, __shfl_xor(m, 16, 64));
    M = fmaxf(M, __shfl_xor(M, 32, 64));
    float sc = __expf(m - M);
    float ss = ssum * sc;
    ss += __shfl_xor(ss, 16, 64);
    ss += __shfl_xor(ss, 32, 64);
    h.x *= sc; h.y *= sc; h.z *= sc; h.w *= sc;
    h.x += __shfl_xor(h.x, 16, 64); h.x += __shfl_xor(h.x, 32, 64);
    h.y += __shfl_xor(h.y, 16, 64); h.y += __shfl_xor(h.y, 32, 64);
    h.z += __shfl_xor(h.z, 16, 64); h.z += __shfl_xor(h.z, 32, 64);
    h.w += __shfl_xor(h.w, 16, 64); h.w += __shfl_xor(h.w, 32, 64);

    if (g == 0) {
        float rs = 1.0f / ss;
        bool has = end > beg;
        float4 o;
        o.x = has ? h.x * rs : 0.f;
        o.y = has ? h.y * rs : 0.f;
        o.z = has ? h.z * rs : 0.f;
        o.w = has ? h.w * rs : 0.f;
        o.x = (o.x > 0.f) ? o.x : (__expf(o.x) - 1.f);
        o.y = (o.y > 0.f) ? o.y : (__expf(o.y) - 1.f);
        o.z = (o.z > 0.f) ? o.z : (__expf(o.z) - 1.f);
        o.w = (o.w > 0.f) ? o.w : (__expf(o.w) - 1.f);
        *(float4*)&out[(size_t)node * F + i * 4] = o;
    }
}

extern "C" void kernel_launch(void* const* d_in, const int* in_sizes, int n_in,
                              void* d_out, int out_size, void* d_ws, size_t ws_size,
                              hipStream_t stream) {
    const float* m_sim = (const float*)d_in[0];
    const float* d_sim = (const float*)d_in[1];
    const float* Wm    = (const float*)d_in[2];
    const float* Wd    = (const float*)d_in[3];
    const int*   src   = (const int*)d_in[4];
    const int*   dst   = (const int*)d_in[5];
    int E = in_sizes[4];
    float* out = (float*)d_out;

    char* ws = (char*)d_ws;
    float* z      = (float*)ws; ws += (size_t)NN * F * 4;
    int*   offs   = (int*)ws;   ws += (size_t)(NN + 1) * 4;
    int*   bbase  = (int*)ws;   ws += 512 * 4;
    int*   bcur   = (int*)ws;   ws += 512 * 4;
    int*   csr    = (int*)ws;   ws += (size_t)E * 4;
    int*   pkb_g  = (int*)ws;   ws += (size_t)NBUCK * BCAP * 4;

    hipMemsetAsync(bcur, 0, 512 * 4, stream);

    int nchunks = (E + CH - 1) / CH;   // 391
    fused1<<<nchunks + NPROJ, 256, 0, stream>>>(m_sim, d_sim, Wm, Wd, z,
                                                src, dst, pkb_g, bcur, nchunks, E);
    scanBuck<<<1, 512, 0, stream>>>(bcur, bbase);
    scatter3<<<NBUCK, 256, 0, stream>>>(pkb_g, bcur, bbase, offs, csr);
    gat_kernel<<<NN / 4, 256, 0, stream>>>(z, offs, csr, out);
}

// Round 17
// 129.017 us; speedup vs baseline: 1.6965x; 1.1471x over previous
//
#include <hip/hip_runtime.h>
#include <math.h>

#define NM 50000
#define ND 50000
#define NN 100000   // total nodes
#define DK 256      // feature dim of both sims
#define F  64       // attn feature size
#define SLOPE 0.2f

#define NBZ   391   // ceil(50000/128) proj blocks per half (128 rows/block)
#define NPROJ (NBZ * 2)

// edge binning: 256-node buckets
#define NBUCK 391   // ceil(100000/256)
#define BCAP  8192  // per-bucket capacity (avg fill 4092)
#define CH    4096  // edges per bin block

typedef short bf16x8 __attribute__((ext_vector_type(8)));
typedef float f32x4  __attribute__((ext_vector_type(4)));

// fp32 -> (hi, lo) bf16 split, rne both halves
__device__ __forceinline__ void cvt8(const float4& a0, const float4& a1,
                                     bf16x8& hi, bf16x8& lo) {
    float v[8] = {a0.x, a0.y, a0.z, a0.w, a1.x, a1.y, a1.z, a1.w};
    #pragma unroll
    for (int e = 0; e < 8; ++e) {
        unsigned u  = __float_as_uint(v[e]);
        unsigned r  = u + 0x7FFF + ((u >> 16) & 1);
        unsigned short hb = (unsigned short)(r >> 16);
        float hf = __uint_as_float(((unsigned)hb) << 16);
        float lf = v[e] - hf;
        unsigned ul = __float_as_uint(lf);
        unsigned rl = ul + 0x7FFF + ((ul >> 16) & 1);
        hi[e] = (short)hb;
        lo[e] = (short)(rl >> 16);
    }
}

// ================= fused kernel 1: bin (blocks 0..nchunks-1) ∥ proj (rest) =================
// R16 diagnosis: proj path latency-bound (Occ 20%, every K-step stalled — A-dbuf
// covers ~400cyc of ~900cyc HBM latency). Fix: A never needed LDS (each wave
// reads only its own 16 rows) -> direct per-lane global loads (wave covers 16
// full 128B lines = minimal transactions), 2-step register prefetch (~600cyc
// cover), ZERO barriers in the K-loop (W-LDS read-only after prologue).
// 512-thr blocks (8 waves, 128 rows), W hi/lo LDS = 64KB -> 2 blocks/CU = 16
// waves/CU if VGPR<=128 (est ~100). bin path = R10-verified 512-thr binning.
__global__ __launch_bounds__(512, 1) void fused1(const float* __restrict__ m_sim,
                                                 const float* __restrict__ d_sim,
                                                 const float* __restrict__ Wm,
                                                 const float* __restrict__ Wd,
                                                 float* __restrict__ z,
                                                 const int* __restrict__ src,
                                                 const int* __restrict__ dst,
                                                 int* __restrict__ pkb_g,
                                                 int* __restrict__ bcur,
                                                 int nchunks, int E) {
    __shared__ __align__(16) char smem[65536];   // 64 KB union
    int t = threadIdx.x;

    if ((int)blockIdx.x < nchunks) {
        // ---------------- bin path (512 threads, ~40 KB) ----------------
        int* cnt   = (int*)smem;          // 512
        int* scx   = cnt + 512;           // 512
        int* lcur  = scx + 512;           // 512
        int* gbase = lcur + 512;          // 512
        int* pkb_l = gbase + 512;         // 4096
        int* bkt_l = pkb_l + CH;          // 4096

        int base = blockIdx.x * CH;
        int chunkN = E - base; if (chunkN > CH) chunkN = CH;

        cnt[t] = 0;
        __syncthreads();

        int ss[8], ds[8];
        #pragma unroll
        for (int e = 0; e < 8; ++e) {
            int k = base + e * 512 + t;
            if (e * 512 + t < chunkN) {
                ds[e] = dst[k];
                ss[e] = src[k];
                atomicAdd(&cnt[ds[e] >> 8], 1);
            }
        }
        __syncthreads();

        int x = cnt[t];
        scx[t] = x;
        __syncthreads();
        for (int off = 1; off < 512; off <<= 1) {
            int v = (t >= off) ? scx[t - off] : 0;
            __syncthreads();
            scx[t] += v;
            __syncthreads();
        }
        int lexcl = scx[t] - x;
        scx[t] = lexcl;
        lcur[t] = lexcl;
        gbase[t] = atomicAdd(&bcur[t], x);
        __syncthreads();

        #pragma unroll
        for (int e = 0; e < 8; ++e) {
            if (e * 512 + t < chunkN) {
                int b = ds[e] >> 8;
                int p = atomicAdd(&lcur[b], 1);
                pkb_l[p] = (ss[e] << 8) | (ds[e] & 255);
                bkt_l[p] = b;
            }
        }
        __syncthreads();

        for (int idx = t; idx < chunkN; idx += 512) {
            int b = bkt_l[idx];
            int g = b * BCAP + gbase[b] + (idx - scx[b]);
            pkb_g[g] = pkb_l[idx];
        }
        return;
    }

    // ---------------- proj path (512 threads, 64 KB) ----------------
    short* Whi = (short*)smem;            // 64 x 256 bf16 = 32 KB, ps = ls^(row&7)
    short* Wlo = (short*)(smem + 32768);  // 32 KB

    int bid  = blockIdx.x - nchunks;
    bool ism = bid < NBZ;
    const float* sim = ism ? m_sim : d_sim;
    const float* W   = ism ? Wm : Wd;
    int row0   = (ism ? bid : bid - NBZ) * 128;
    int nrows  = ism ? NM : ND;
    int zbase  = ism ? 0 : NM;

    int l = t & 63;           // lane
    int w = t >> 6;           // wave 0..7
    int frow = l & 15;        // A row within wave stripe / B col within tile
    int kg   = l >> 4;        // k-group 0..3

    // direct A-load pointer: lane reads sim[grow][step*32 + kg*8 .. +8]
    int grow = row0 + w * 16 + frow; if (grow > nrows - 1) grow = nrows - 1;
    const float4* ap = (const float4*)(sim + (size_t)grow * DK) + kg * 2;

    // prefetch steps 0 and 1 (issued before W conversion; land during it)
    float4 pa0 = ap[0], pa1 = ap[1];
    float4 pb0 = ap[8], pb1 = ap[9];

    // ---- W -> LDS bf16 hi+lo, once per block (write-side XOR ps = ls^(r&7)) ----
    {
        int r = t >> 3;                   // row 0..63
        int q = t & 7;                    // slot quarter 0..7
        const float4* wr = (const float4*)(W + (size_t)r * DK);
        #pragma unroll
        for (int i = 0; i < 4; ++i) {
            int ls = q * 4 + i;           // logical slot 0..31
            float4 b0 = wr[ls * 2], b1 = wr[ls * 2 + 1];
            bf16x8 hi, lo;
            cvt8(b0, b1, hi, lo);
            int ps = ls ^ (r & 7);
            *(bf16x8*)&Whi[r * 256 + ps * 8] = hi;
            *(bf16x8*)&Wlo[r * 256 + ps * 8] = lo;
        }
    }
    __syncthreads();   // W tiles ready; no further barriers needed

    f32x4 acc[4];
    #pragma unroll
    for (int j = 0; j < 4; ++j) acc[j] = (f32x4){0.f, 0.f, 0.f, 0.f};

    #pragma unroll 1
    for (int step = 0; step < 8; ++step) {
        bf16x8 ahi, alo;
        cvt8(pa0, pa1, ahi, alo);
        // rotate prefetch; issue step+2 loads (2 iterations of cover)
        pa0 = pb0; pa1 = pb1;
        if (step + 2 < 8) {
            pb0 = ap[(step + 2) * 8];
            pb1 = ap[(step + 2) * 8 + 1];
        }

        int ls = step * 4 + kg;
        #pragma unroll
        for (int j = 0; j < 4; ++j) {
            int wrow = j * 16 + frow;
            int ps = ls ^ (wrow & 7);
            bf16x8 bhi = *(const bf16x8*)&Whi[wrow * 256 + ps * 8];
            bf16x8 blo = *(const bf16x8*)&Wlo[wrow * 256 + ps * 8];
            acc[j] = __builtin_amdgcn_mfma_f32_16x16x32_bf16(ahi, bhi, acc[j], 0, 0, 0);
            acc[j] = __builtin_amdgcn_mfma_f32_16x16x32_bf16(ahi, blo, acc[j], 0, 0, 0);
            acc[j] = __builtin_amdgcn_mfma_f32_16x16x32_bf16(alo, bhi, acc[j], 0, 0, 0);
        }
    }

    // D layout (verified m89): col = lane&15, row = (lane>>4)*4 + reg
    #pragma unroll
    for (int j = 0; j < 4; ++j) {
        #pragma unroll
        for (int reg = 0; reg < 4; ++reg) {
            int r = row0 + w * 16 + kg * 4 + reg;
            if (r < nrows)
                z[(size_t)(zbase + r) * F + j * 16 + frow] = acc[j][reg];
        }
    }
}

// ---------------- exclusive scan of bucket totals ----------------
__global__ __launch_bounds__(512) void scanBuck(const int* __restrict__ bcur,
                                                int* __restrict__ bbase) {
    __shared__ int sd[512];
    int t = threadIdx.x;
    int x = (t < NBUCK) ? bcur[t] : 0;
    sd[t] = x;
    __syncthreads();
    for (int off = 1; off < 512; off <<= 1) {
        int v = (t >= off) ? sd[t - off] : 0;
        __syncthreads();
        sd[t] += v;
        __syncthreads();
    }
    if (t < NBUCK) bbase[t] = sd[t] - x;
}

// ---------------- per-bucket: degree hist + local scan + offs + scatter ----------------
__global__ __launch_bounds__(256) void scatter3(const int* __restrict__ pkb_g,
                                                const int* __restrict__ bcur,
                                                const int* __restrict__ bbase,
                                                int* __restrict__ offs,
                                                int* __restrict__ csr) {
    __shared__ int dcnt[256], loc[256], lcur[256];
    int b = blockIdx.x;
    int t = threadIdx.x;
    int node0 = b << 8;
    int nbe  = bcur[b];
    int base = bbase[b];
    const int* pp = pkb_g + (size_t)b * BCAP;

    dcnt[t] = 0;
    __syncthreads();
    for (int i = t; i < nbe; i += 256)
        atomicAdd(&dcnt[pp[i] & 255], 1);
    __syncthreads();

    int x = dcnt[t];
    loc[t] = x;
    __syncthreads();
    for (int off = 1; off < 256; off <<= 1) {
        int v = (t >= off) ? loc[t - off] : 0;
        __syncthreads();
        loc[t] += v;
        __syncthreads();
    }
    int excl = loc[t] - x;
    int node = node0 + t;
    if (node < NN) offs[node] = base + excl;
    if (b == NBUCK - 1 && t == 0) offs[NN] = base + nbe;
    lcur[t] = base + excl;
    __syncthreads();

    for (int i = t; i < nbe; i += 256) {
        int pk = pp[i];
        int pos = atomicAdd(&lcur[pk & 255], 1);
        csr[pos] = pk >> 8;
    }
}

// ---------------- fused per-dst-node: scores + online softmax + aggregation + elu ----------------
// Wave per node, 4 groups x 16 lanes. 16 edges per iteration (4 per group slot):
// 4 gathers in flight per wave (R16: 2) -> halves exposed L3 latency.
__global__ __launch_bounds__(256) void gat_kernel(const float* __restrict__ z,
                                                  const int* __restrict__ offs,
                                                  const int* __restrict__ csr_src,
                                                  float* __restrict__ out) {
    int tid  = threadIdx.x;
    int node = blockIdx.x * 4 + (tid >> 6);
    int lane = tid & 63;
    int g    = lane >> 4;     // edge slot 0..3
    int i    = lane & 15;     // feature quad 0..15
    int beg = offs[node];
    int end = offs[node + 1];

    float4 zd = *(const float4*)&z[(size_t)node * F + i * 4];

    float  m = -1e30f, ssum = 0.f;
    float4 h = {0.f, 0.f, 0.f, 0.f};

    for (int j = beg; j < end; j += 16) {
        int   idx[4];
        bool  val[4];
        float4 v[4];
        float p[4], e[4], ex[4];
        #pragma unroll
        for (int k = 0; k < 4; ++k) {
            int jj = j + k * 4 + g;
            val[k] = jj < end;
            idx[k] = csr_src[val[k] ? jj : beg];
        }
        #pragma unroll
        for (int k = 0; k < 4; ++k)
            v[k] = *(const float4*)&z[(size_t)idx[k] * F + i * 4];
        #pragma unroll
        for (int k = 0; k < 4; ++k)
            p[k] = v[k].x * zd.x + v[k].y * zd.y + v[k].z * zd.z + v[k].w * zd.w;
        #pragma unroll
        for (int o = 1; o < 16; o <<= 1) {
            #pragma unroll
            for (int k = 0; k < 4; ++k) p[k] += __shfl_xor(p[k], o, 64);
        }
        #pragma unroll
        for (int k = 0; k < 4; ++k) {
            float ek = (p[k] > 0.f) ? p[k] : SLOPE * p[k];
            e[k] = val[k] ? ek : -1e30f;
        }
        float nm = fmaxf(m, fmaxf(fmaxf(e[0], e[1]), fmaxf(e[2], e[3])));
        float sc = __expf(m - nm);
        #pragma unroll
        for (int k = 0; k < 4; ++k) ex[k] = val[k] ? __expf(e[k] - nm) : 0.f;
        ssum = ssum * sc + ex[0] + ex[1] + ex[2] + ex[3];
        h.x = h.x * sc + ex[0] * v[0].x + ex[1] * v[1].x + ex[2] * v[2].x + ex[3] * v[3].x;
        h.y = h.y * sc + ex[0] * v[0].y + ex[1] * v[1].y + ex[2] * v[2].y + ex[3] * v[3].y;
        h.z = h.z * sc + ex[0] * v[0].z + ex[1] * v[1].z + ex[2] * v[2].z + ex[3] * v[3].z;
        h.w = h.w * sc + ex[0] * v[0].w + ex[1] * v[1].w + ex[2] * v[2].w + ex[3] * v[3].w;
        m = nm;
    }

    float M = fmaxf(m, __shfl_xor(m, 16, 64));
    M = fmaxf(M, __shfl_xor(M, 32, 64));
    float sc = __expf(m - M);
    float ss = ssum * sc;
    ss += __shfl_xor(ss, 16, 64);
    ss += __shfl_xor(ss, 32, 64);
    h.x *= sc; h.y *= sc; h.z *= sc; h.w *= sc;
    h.x += __shfl_xor(h.x, 16, 64); h.x += __shfl_xor(h.x, 32, 64);
    h.y += __shfl_xor(h.y, 16, 64); h.y += __shfl_xor(h.y, 32, 64);
    h.z += __shfl_xor(h.z, 16, 64); h.z += __shfl_xor(h.z, 32, 64);
    h.w += __shfl_xor(h.w, 16, 64); h.w += __shfl_xor(h.w, 32, 64);

    if (g == 0) {
        float rs = 1.0f / ss;
        bool has = end > beg;
        float4 o;
        o.x = has ? h.x * rs : 0.f;
        o.y = has ? h.y * rs : 0.f;
        o.z = has ? h.z * rs : 0.f;
        o.w = has ? h.w * rs : 0.f;
        o.x = (o.x > 0.f) ? o.x : (__expf(o.x) - 1.f);
        o.y = (o.y > 0.f) ? o.y : (__expf(o.y) - 1.f);
        o.z = (o.z > 0.f) ? o.z : (__expf(o.z) - 1.f);
        o.w = (o.w > 0.f) ? o.w : (__expf(o.w) - 1.f);
        *(float4*)&out[(size_t)node * F + i * 4] = o;
    }
}

extern "C" void kernel_launch(void* const* d_in, const int* in_sizes, int n_in,
                              void* d_out, int out_size, void* d_ws, size_t ws_size,
                              hipStream_t stream) {
    const float* m_sim = (const float*)d_in[0];
    const float* d_sim = (const float*)d_in[1];
    const float* Wm    = (const float*)d_in[2];
    const float* Wd    = (const float*)d_in[3];
    const int*   src   = (const int*)d_in[4];
    const int*   dst   = (const int*)d_in[5];
    int E = in_sizes[4];
    float* out = (float*)d_out;

    char* ws = (char*)d_ws;
    float* z      = (float*)ws; ws += (size_t)NN * F * 4;
    int*   offs   = (int*)ws;   ws += (size_t)(NN + 1) * 4;
    int*   bbase  = (int*)ws;   ws += 512 * 4;
    int*   bcur   = (int*)ws;   ws += 512 * 4;
    int*   csr    = (int*)ws;   ws += (size_t)E * 4;
    int*   pkb_g  = (int*)ws;   ws += (size_t)NBUCK * BCAP * 4;

    hipMemsetAsync(bcur, 0, 512 * 4, stream);

    int nchunks = (E + CH - 1) / CH;   // 391
    fused1<<<nchunks + NPROJ, 512, 0, stream>>>(m_sim, d_sim, Wm, Wd, z,
                                                src, dst, pkb_g, bcur, nchunks, E);
    scanBuck<<<1, 512, 0, stream>>>(bcur, bbase);
    scatter3<<<NBUCK, 256, 0, stream>>>(pkb_g, bcur, bbase, offs, csr);
    gat_kernel<<<NN / 4, 256, 0, stream>>>(z, offs, csr, out);
}

// Round 18
// 128.103 us; speedup vs baseline: 1.7086x; 1.0071x over previous
//
#include <hip/hip_runtime.h>
#include <math.h>

#define NM 50000
#define ND 50000
#define NN 100000   // total nodes
#define DK 256      // feature dim of both sims
#define F  64       // attn feature size
#define SLOPE 0.2f

#define NBZ   391   // ceil(50000/128) proj blocks per half (128 rows/block)
#define NPROJ (NBZ * 2)

// edge binning: 256-node buckets
#define NBUCK 391   // ceil(100000/256)
#define BCAP  8192  // per-bucket capacity (avg fill 4092)
#define CH    4096  // edges per bin block

typedef short bf16x8 __attribute__((ext_vector_type(8)));
typedef float f32x4  __attribute__((ext_vector_type(4)));

// fp32 -> (hi, lo) bf16 split, rne both halves
__device__ __forceinline__ void cvt8(const float4& a0, const float4& a1,
                                     bf16x8& hi, bf16x8& lo) {
    float v[8] = {a0.x, a0.y, a0.z, a0.w, a1.x, a1.y, a1.z, a1.w};
    #pragma unroll
    for (int e = 0; e < 8; ++e) {
        unsigned u  = __float_as_uint(v[e]);
        unsigned r  = u + 0x7FFF + ((u >> 16) & 1);
        unsigned short hb = (unsigned short)(r >> 16);
        float hf = __uint_as_float(((unsigned)hb) << 16);
        float lf = v[e] - hf;
        unsigned ul = __float_as_uint(lf);
        unsigned rl = ul + 0x7FFF + ((ul >> 16) & 1);
        hi[e] = (short)hb;
        lo[e] = (short)(rl >> 16);
    }
}

// ================= fused kernel 1: bin (blocks 0..nchunks-1) ∥ proj (rest) =================
// R17: proj path still latency-bound (Occ 31.6%) — 2-deep prefetch covers ~500
// of ~900cyc. v3: 4-deep rolling prefetch (4 named pairs, full-unroll 8 steps,
// consume p[s&3] then reload with step s+4): ~1200cyc cover. +32 VGPR (~90
// total, <128 -> 2 blocks/CU kept).
__global__ __launch_bounds__(512, 1) void fused1(const float* __restrict__ m_sim,
                                                 const float* __restrict__ d_sim,
                                                 const float* __restrict__ Wm,
                                                 const float* __restrict__ Wd,
                                                 float* __restrict__ z,
                                                 const int* __restrict__ src,
                                                 const int* __restrict__ dst,
                                                 int* __restrict__ pkb_g,
                                                 int* __restrict__ bcur,
                                                 int nchunks, int E) {
    __shared__ __align__(16) char smem[65536];   // 64 KB union
    int t = threadIdx.x;

    if ((int)blockIdx.x < nchunks) {
        // ---------------- bin path (512 threads, ~40 KB) ----------------
        int* cnt   = (int*)smem;          // 512
        int* scx   = cnt + 512;           // 512
        int* lcur  = scx + 512;           // 512
        int* gbase = lcur + 512;          // 512
        int* pkb_l = gbase + 512;         // 4096
        int* bkt_l = pkb_l + CH;          // 4096

        int base = blockIdx.x * CH;
        int chunkN = E - base; if (chunkN > CH) chunkN = CH;

        cnt[t] = 0;
        __syncthreads();

        int ss[8], ds[8];
        #pragma unroll
        for (int e = 0; e < 8; ++e) {
            int k = base + e * 512 + t;
            if (e * 512 + t < chunkN) {
                ds[e] = dst[k];
                ss[e] = src[k];
                atomicAdd(&cnt[ds[e] >> 8], 1);
            }
        }
        __syncthreads();

        int x = cnt[t];
        scx[t] = x;
        __syncthreads();
        for (int off = 1; off < 512; off <<= 1) {
            int v = (t >= off) ? scx[t - off] : 0;
            __syncthreads();
            scx[t] += v;
            __syncthreads();
        }
        int lexcl = scx[t] - x;
        scx[t] = lexcl;
        lcur[t] = lexcl;
        gbase[t] = atomicAdd(&bcur[t], x);
        __syncthreads();

        #pragma unroll
        for (int e = 0; e < 8; ++e) {
            if (e * 512 + t < chunkN) {
                int b = ds[e] >> 8;
                int p = atomicAdd(&lcur[b], 1);
                pkb_l[p] = (ss[e] << 8) | (ds[e] & 255);
                bkt_l[p] = b;
            }
        }
        __syncthreads();

        for (int idx = t; idx < chunkN; idx += 512) {
            int b = bkt_l[idx];
            int g = b * BCAP + gbase[b] + (idx - scx[b]);
            pkb_g[g] = pkb_l[idx];
        }
        return;
    }

    // ---------------- proj path (512 threads, 64 KB) ----------------
    short* Whi = (short*)smem;            // 64 x 256 bf16 = 32 KB, ps = ls^(row&7)
    short* Wlo = (short*)(smem + 32768);  // 32 KB

    int bid  = blockIdx.x - nchunks;
    bool ism = bid < NBZ;
    const float* sim = ism ? m_sim : d_sim;
    const float* W   = ism ? Wm : Wd;
    int row0   = (ism ? bid : bid - NBZ) * 128;
    int nrows  = ism ? NM : ND;
    int zbase  = ism ? 0 : NM;

    int l = t & 63;           // lane
    int w = t >> 6;           // wave 0..7
    int frow = l & 15;        // A row within wave stripe / B col within tile
    int kg   = l >> 4;        // k-group 0..3

    // direct A-load pointer: lane reads sim[grow][step*32 + kg*8 .. +8]
    int grow = row0 + w * 16 + frow; if (grow > nrows - 1) grow = nrows - 1;
    const float4* ap = (const float4*)(sim + (size_t)grow * DK) + kg * 2;

    // 4-deep prefetch: steps 0..3 in flight before W conversion
    float4 p0a = ap[0],  p0b = ap[1];
    float4 p1a = ap[8],  p1b = ap[9];
    float4 p2a = ap[16], p2b = ap[17];
    float4 p3a = ap[24], p3b = ap[25];

    // ---- W -> LDS bf16 hi+lo, once per block (write-side XOR ps = ls^(r&7)) ----
    {
        int r = t >> 3;                   // row 0..63
        int q = t & 7;                    // slot quarter 0..7
        const float4* wr = (const float4*)(W + (size_t)r * DK);
        #pragma unroll
        for (int i = 0; i < 4; ++i) {
            int ls = q * 4 + i;           // logical slot 0..31
            float4 b0 = wr[ls * 2], b1 = wr[ls * 2 + 1];
            bf16x8 hi, lo;
            cvt8(b0, b1, hi, lo);
            int ps = ls ^ (r & 7);
            *(bf16x8*)&Whi[r * 256 + ps * 8] = hi;
            *(bf16x8*)&Wlo[r * 256 + ps * 8] = lo;
        }
    }
    __syncthreads();   // W tiles ready; no further barriers needed

    f32x4 acc[4];
    #pragma unroll
    for (int j = 0; j < 4; ++j) acc[j] = (f32x4){0.f, 0.f, 0.f, 0.f};

    // one K-step: consume (pa,pb), do 12 MFMA against W slots (ls = step*4+kg)
    #define PROJ_STEP(STEP, PA, PB)                                              \
    {                                                                            \
        bf16x8 ahi, alo;                                                         \
        cvt8(PA, PB, ahi, alo);                                                  \
        if (STEP + 4 < 8) {                                                      \
            PA = ap[(STEP + 4) * 8];                                             \
            PB = ap[(STEP + 4) * 8 + 1];                                         \
        }                                                                        \
        int ls = STEP * 4 + kg;                                                  \
        _Pragma("unroll")                                                        \
        for (int j = 0; j < 4; ++j) {                                            \
            int wrow = j * 16 + frow;                                            \
            int ps = ls ^ (wrow & 7);                                            \
            bf16x8 bhi = *(const bf16x8*)&Whi[wrow * 256 + ps * 8];              \
            bf16x8 blo = *(const bf16x8*)&Wlo[wrow * 256 + ps * 8];              \
            acc[j] = __builtin_amdgcn_mfma_f32_16x16x32_bf16(ahi, bhi, acc[j], 0, 0, 0); \
            acc[j] = __builtin_amdgcn_mfma_f32_16x16x32_bf16(ahi, blo, acc[j], 0, 0, 0); \
            acc[j] = __builtin_amdgcn_mfma_f32_16x16x32_bf16(alo, bhi, acc[j], 0, 0, 0); \
        }                                                                        \
    }

    PROJ_STEP(0, p0a, p0b)
    PROJ_STEP(1, p1a, p1b)
    PROJ_STEP(2, p2a, p2b)
    PROJ_STEP(3, p3a, p3b)
    PROJ_STEP(4, p0a, p0b)
    PROJ_STEP(5, p1a, p1b)
    PROJ_STEP(6, p2a, p2b)
    PROJ_STEP(7, p3a, p3b)
    #undef PROJ_STEP

    // D layout (verified m89): col = lane&15, row = (lane>>4)*4 + reg
    #pragma unroll
    for (int j = 0; j < 4; ++j) {
        #pragma unroll
        for (int reg = 0; reg < 4; ++reg) {
            int r = row0 + w * 16 + kg * 4 + reg;
            if (r < nrows)
                z[((zbase + r) << 6) + j * 16 + frow] = acc[j][reg];
        }
    }
}

// ---------------- exclusive scan of bucket totals ----------------
__global__ __launch_bounds__(512) void scanBuck(const int* __restrict__ bcur,
                                                int* __restrict__ bbase) {
    __shared__ int sd[512];
    int t = threadIdx.x;
    int x = (t < NBUCK) ? bcur[t] : 0;
    sd[t] = x;
    __syncthreads();
    for (int off = 1; off < 512; off <<= 1) {
        int v = (t >= off) ? sd[t - off] : 0;
        __syncthreads();
        sd[t] += v;
        __syncthreads();
    }
    if (t < NBUCK) bbase[t] = sd[t] - x;
}

// ---------------- per-bucket: degree hist + local scan + offs + scatter ----------------
__global__ __launch_bounds__(256) void scatter3(const int* __restrict__ pkb_g,
                                                const int* __restrict__ bcur,
                                                const int* __restrict__ bbase,
                                                int* __restrict__ offs,
                                                int* __restrict__ csr) {
    __shared__ int dcnt[256], loc[256], lcur[256];
    int b = blockIdx.x;
    int t = threadIdx.x;
    int node0 = b << 8;
    int nbe  = bcur[b];
    int base = bbase[b];
    const int* pp = pkb_g + (size_t)b * BCAP;

    dcnt[t] = 0;
    __syncthreads();
    for (int i = t; i < nbe; i += 256)
        atomicAdd(&dcnt[pp[i] & 255], 1);
    __syncthreads();

    int x = dcnt[t];
    loc[t] = x;
    __syncthreads();
    for (int off = 1; off < 256; off <<= 1) {
        int v = (t >= off) ? loc[t - off] : 0;
        __syncthreads();
        loc[t] += v;
        __syncthreads();
    }
    int excl = loc[t] - x;
    int node = node0 + t;
    if (node < NN) offs[node] = base + excl;
    if (b == NBUCK - 1 && t == 0) offs[NN] = base + nbe;
    lcur[t] = base + excl;
    __syncthreads();

    for (int i = t; i < nbe; i += 256) {
        int pk = pp[i];
        int pos = atomicAdd(&lcur[pk & 255], 1);
        csr[pos] = pk >> 8;
    }
}

// ---------------- fused per-dst-node: scores + online softmax + aggregation + elu ----------------
// R17: VALUBusy 79% = VALU-throughput-bound; dominant overhead is 64-bit address
// chains on every gather. v5: all z/out accesses via 32-bit offsets from the
// base pointer ((idx<<6)+(i<<2) floats) -> saddr+voffset addressing.
__global__ __launch_bounds__(256) void gat_kernel(const float* __restrict__ z,
                                                  const int* __restrict__ offs,
                                                  const int* __restrict__ csr_src,
                                                  float* __restrict__ out) {
    int tid  = threadIdx.x;
    int node = blockIdx.x * 4 + (tid >> 6);
    int lane = tid & 63;
    int g    = lane >> 4;     // edge slot 0..3
    int i    = lane & 15;     // feature quad 0..15
    int beg = offs[node];
    int end = offs[node + 1];
    int iq  = i << 2;         // feature-quad float offset

    float4 zd = *(const float4*)(z + (node << 6) + iq);

    float  m = -1e30f, ssum = 0.f;
    float4 h = {0.f, 0.f, 0.f, 0.f};

    for (int j = beg; j < end; j += 16) {
        int   off_[4];
        bool  val[4];
        float4 v[4];
        float p[4], e[4], ex[4];
        #pragma unroll
        for (int k = 0; k < 4; ++k) {
            int jj = j + k * 4 + g;
            val[k] = jj < end;
            off_[k] = (csr_src[val[k] ? jj : beg] << 6) + iq;   // 32-bit offset
        }
        #pragma unroll
        for (int k = 0; k < 4; ++k)
            v[k] = *(const float4*)(z + off_[k]);
        #pragma unroll
        for (int k = 0; k < 4; ++k)
            p[k] = v[k].x * zd.x + v[k].y * zd.y + v[k].z * zd.z + v[k].w * zd.w;
        #pragma unroll
        for (int o = 1; o < 16; o <<= 1) {
            #pragma unroll
            for (int k = 0; k < 4; ++k) p[k] += __shfl_xor(p[k], o, 64);
        }
        #pragma unroll
        for (int k = 0; k < 4; ++k) {
            float ek = (p[k] > 0.f) ? p[k] : SLOPE * p[k];
            e[k] = val[k] ? ek : -1e30f;
        }
        float nm = fmaxf(m, fmaxf(fmaxf(e[0], e[1]), fmaxf(e[2], e[3])));
        float sc = __expf(m - nm);
        #pragma unroll
        for (int k = 0; k < 4; ++k) ex[k] = val[k] ? __expf(e[k] - nm) : 0.f;
        ssum = ssum * sc + ex[0] + ex[1] + ex[2] + ex[3];
        h.x = h.x * sc + ex[0] * v[0].x + ex[1] * v[1].x + ex[2] * v[2].x + ex[3] * v[3].x;
        h.y = h.y * sc + ex[0] * v[0].y + ex[1] * v[1].y + ex[2] * v[2].y + ex[3] * v[3].y;
        h.z = h.z * sc + ex[0] * v[0].z + ex[1] * v[1].z + ex[2] * v[2].z + ex[3] * v[3].z;
        h.w = h.w * sc + ex[0] * v[0].w + ex[1] * v[1].w + ex[2] * v[2].w + ex[3] * v[3].w;
        m = nm;
    }

    float M = fmaxf(m, __shfl_xor(m, 16, 64));
    M = fmaxf(M, __shfl_xor(M, 32, 64));
    float sc = __expf(m - M);
    float ss = ssum * sc;
    ss += __shfl_xor(ss, 16, 64);
    ss += __shfl_xor(ss, 32, 64);
    h.x *= sc; h.y *= sc; h.z *= sc; h.w *= sc;
    h.x += __shfl_xor(h.x, 16, 64); h.x += __shfl_xor(h.x, 32, 64);
    h.y += __shfl_xor(h.y, 16, 64); h.y += __shfl_xor(h.y, 32, 64);
    h.z += __shfl_xor(h.z, 16, 64); h.z += __shfl_xor(h.z, 32, 64);
    h.w += __shfl_xor(h.w, 16, 64); h.w += __shfl_xor(h.w, 32, 64);

    if (g == 0) {
        float rs = 1.0f / ss;
        bool has = end > beg;
        float4 o;
        o.x = has ? h.x * rs : 0.f;
        o.y = has ? h.y * rs : 0.f;
        o.z = has ? h.z * rs : 0.f;
        o.w = has ? h.w * rs : 0.f;
        o.x = (o.x > 0.f) ? o.x : (__expf(o.x) - 1.f);
        o.y = (o.y > 0.f) ? o.y : (__expf(o.y) - 1.f);
        o.z = (o.z > 0.f) ? o.z : (__expf(o.z) - 1.f);
        o.w = (o.w > 0.f) ? o.w : (__expf(o.w) - 1.f);
        *(float4*)(out + (node << 6) + iq) = o;
    }
}

extern "C" void kernel_launch(void* const* d_in, const int* in_sizes, int n_in,
                              void* d_out, int out_size, void* d_ws, size_t ws_size,
                              hipStream_t stream) {
    const float* m_sim = (const float*)d_in[0];
    const float* d_sim = (const float*)d_in[1];
    const float* Wm    = (const float*)d_in[2];
    const float* Wd    = (const float*)d_in[3];
    const int*   src   = (const int*)d_in[4];
    const int*   dst   = (const int*)d_in[5];
    int E = in_sizes[4];
    float* out = (float*)d_out;

    char* ws = (char*)d_ws;
    float* z      = (float*)ws; ws += (size_t)NN * F * 4;
    int*   offs   = (int*)ws;   ws += (size_t)(NN + 1) * 4;
    int*   bbase  = (int*)ws;   ws += 512 * 4;
    int*   bcur   = (int*)ws;   ws += 512 * 4;
    int*   csr    = (int*)ws;   ws += (size_t)E * 4;
    int*   pkb_g  = (int*)ws;   ws += (size_t)NBUCK * BCAP * 4;

    hipMemsetAsync(bcur, 0, 512 * 4, stream);

    int nchunks = (E + CH - 1) / CH;   // 391
    fused1<<<nchunks + NPROJ, 512, 0, stream>>>(m_sim, d_sim, Wm, Wd, z,
                                                src, dst, pkb_g, bcur, nchunks, E);
    scanBuck<<<1, 512, 0, stream>>>(bcur, bbase);
    scatter3<<<NBUCK, 256, 0, stream>>>(pkb_g, bcur, bbase, offs, csr);
    gat_kernel<<<NN / 4, 256, 0, stream>>>(z, offs, csr, out);
}